// Round 7
// baseline (525.709 us; speedup 1.0000x reference)
//
#include <hip/hip_runtime.h>
#include <cstdint>
#include <cstddef>

// Problem constants
#define TB_B 4
#define TB_S 1024
#define TB_E 1024
#define TB_H 16
#define TB_D 64
#define TB_MLP 4096
#define TB_ROWS (TB_B * TB_S)   // 4096

typedef int int4v __attribute__((ext_vector_type(4)));

#define LGKM0() __asm__ volatile("s_waitcnt lgkmcnt(0)" ::: "memory")
#define CMEMBAR() __asm__ volatile("" ::: "memory")
// raw barrier with compiler memory fences (no vmcnt drain, unlike __syncthreads)
#define RAW_BARRIER() do { __asm__ volatile("" ::: "memory"); \
  __builtin_amdgcn_s_barrier(); __asm__ volatile("" ::: "memory"); } while (0)

static __device__ __forceinline__ void atomicMaxF(float* addr, float v) {
  // valid for non-negative floats: IEEE bit pattern is monotonic
  atomicMax(reinterpret_cast<unsigned int*>(addr), __float_as_uint(v));
}

static __device__ __forceinline__ float fast_exp2(float x) {
#if __has_builtin(__builtin_amdgcn_exp2f)
  return __builtin_amdgcn_exp2f(x);
#else
  return exp2f(x);
#endif
}

// async global->LDS, 16 bytes per lane. LDS dest must be wave-uniform base + lane*16.
static __device__ __forceinline__ void gl2lds16(const void* g, void* l) {
  __builtin_amdgcn_global_load_lds(
      (const __attribute__((address_space(1))) void*)g,
      (__attribute__((address_space(3))) void*)l, 16, 0, 0);
}

// ---------------------------------------------------------------------------
// multi-tensor absmax: one dispatch for all 13 input tensors
// ---------------------------------------------------------------------------
struct AMDesc { const float* p; long n4; int slot; };
struct AMBatch { AMDesc d[13]; };
__global__ __launch_bounds__(256) void absmax_multi_kernel(AMBatch bt, float* ws) {
  AMDesc d = bt.d[blockIdx.y];
  float m = 0.f;
  long stride = (long)gridDim.x * 256;
  for (long i = (long)blockIdx.x * 256 + threadIdx.x; i < d.n4; i += stride) {
    float4 v = ((const float4*)d.p)[i];
    m = fmaxf(m, fmaxf(fmaxf(fabsf(v.x), fabsf(v.y)), fmaxf(fabsf(v.z), fabsf(v.w))));
  }
#pragma unroll
  for (int o = 32; o; o >>= 1) m = fmaxf(m, __shfl_down(m, o, 64));
  __shared__ float sm[4];
  if (!(threadIdx.x & 63)) sm[threadIdx.x >> 6] = m;
  __syncthreads();
  if (threadIdx.x == 0)
    atomicMaxF(ws + d.slot, fmaxf(fmaxf(sm[0], sm[1]), fmaxf(sm[2], sm[3])));
}

// multi-tensor fake-quant -> i8 codes (x + 6 weights)
struct QMDesc { const float* in; signed char* out; long n4; int slot; float qmin; };
struct QMBatch { QMDesc d[7]; };
__global__ __launch_bounds__(256) void quant8_multi_kernel(QMBatch bt, const float* ws) {
  QMDesc d = bt.d[blockIdx.y];
  float scale = fmaxf(ws[d.slot] / 127.f, 1e-8f);
  long stride = (long)gridDim.x * 256;
  for (long i = (long)blockIdx.x * 256 + threadIdx.x; i < d.n4; i += stride) {
    float4 v = ((const float4*)d.in)[i];
    char4 o;
    o.x = (signed char)(int)fminf(fmaxf(rintf(v.x / scale), d.qmin), 127.f);
    o.y = (signed char)(int)fminf(fmaxf(rintf(v.y / scale), d.qmin), 127.f);
    o.z = (signed char)(int)fminf(fmaxf(rintf(v.z / scale), d.qmin), 127.f);
    o.w = (signed char)(int)fminf(fmaxf(rintf(v.w / scale), d.qmin), 127.f);
    ((char4*)d.out)[i] = o;
  }
}

// multi-tensor bias fake-quant -> fp32
struct BDesc { const float* in; float* out; int n4; int slot; };
struct BBatch { BDesc d[6]; };
__global__ __launch_bounds__(256) void bias_quant_multi_kernel(BBatch bt, const float* ws) {
  BDesc d = bt.d[blockIdx.y];
  float scale = fmaxf(ws[d.slot] / 127.f, 1e-8f);
  int i = blockIdx.x * 256 + threadIdx.x;
  if (i < d.n4) {
    float4 v = ((const float4*)d.in)[i];
    float4 o;
    o.x = fminf(fmaxf(rintf(v.x / scale), -128.f), 127.f) * scale;
    o.y = fminf(fmaxf(rintf(v.y / scale), -128.f), 127.f) * scale;
    o.z = fminf(fmaxf(rintf(v.z / scale), -128.f), 127.f) * scale;
    o.w = fminf(fmaxf(rintf(v.w / scale), -128.f), 127.f) * scale;
    ((float4*)d.out)[i] = o;
  }
}

// generic fake-quant -> i8 (same layout)
__global__ __launch_bounds__(256) void quant8_kernel(const float* __restrict__ in,
                                                     signed char* __restrict__ out8, long n4,
                                                     const float* __restrict__ amax_p,
                                                     float pre, float qmin) {
  float scale = fmaxf(amax_p[0] * pre / 127.f, 1e-8f);
  long stride = (long)gridDim.x * 256;
  for (long i = (long)blockIdx.x * 256 + threadIdx.x; i < n4; i += stride) {
    float4 v = ((const float4*)in)[i];
    char4 o;
    o.x = (signed char)(int)fminf(fmaxf(rintf(v.x * pre / scale), qmin), 127.f);
    o.y = (signed char)(int)fminf(fmaxf(rintf(v.y * pre / scale), qmin), 127.f);
    o.z = (signed char)(int)fminf(fmaxf(rintf(v.z * pre / scale), qmin), 127.f);
    o.w = (signed char)(int)fminf(fmaxf(rintf(v.w * pre / scale), qmin), 127.f);
    ((char4*)out8)[i] = o;
  }
}

// relu + unsigned 8-bit quant -> codes stored as (c - 128) in signed i8
__global__ __launch_bounds__(256) void relu_quant8_kernel(const float* __restrict__ in,
                                                          signed char* __restrict__ out8, long n4,
                                                          const float* __restrict__ amax_p) {
  float scale = fmaxf(amax_p[0] / 255.f, 1e-8f);
  long stride = (long)gridDim.x * 256;
  for (long i = (long)blockIdx.x * 256 + threadIdx.x; i < n4; i += stride) {
    float4 v = ((const float4*)in)[i];
    char4 o;
    o.x = (signed char)((int)fminf(fmaxf(rintf(fmaxf(v.x, 0.f) / scale), 0.f), 255.f) - 128);
    o.y = (signed char)((int)fminf(fmaxf(rintf(fmaxf(v.y, 0.f) / scale), 0.f), 255.f) - 128);
    o.z = (signed char)((int)fminf(fmaxf(rintf(fmaxf(v.z, 0.f) / scale), 0.f), 255.f) - 128);
    o.w = (signed char)((int)fminf(fmaxf(rintf(fmaxf(v.w, 0.f) / scale), 0.f), 255.f) - 128);
    ((char4*)out8)[i] = o;
  }
}

// per-row sum of int8 codes (for unsigned-offset correction); one block per row
__global__ __launch_bounds__(256) void rowsum_i8_kernel(const signed char* __restrict__ w8,
                                                        int* __restrict__ out, int Kdim) {
  const int row = blockIdx.x, t = threadIdx.x;
  const signed char* p = w8 + (long)row * Kdim;
  int s = 0;
  for (int i = t * 16; i < Kdim; i += 4096) {
    int4v v = *(const int4v*)(p + i);
    const signed char* b = (const signed char*)&v;
#pragma unroll
    for (int j = 0; j < 16; j++) s += b[j];
  }
#pragma unroll
  for (int o = 32; o; o >>= 1) s += __shfl_down(s, o, 64);
  __shared__ int sm[4];
  if (!(t & 63)) sm[t >> 6] = s;
  __syncthreads();
  if (t == 0) out[row] = sm[0] + sm[1] + sm[2] + sm[3];
}

// ---------------------------------------------------------------------------
// int8 MFMA NT GEMM (exact): C[M,N] = (sum_k A8[m,k]*B8[n,k] + corr) * s_a*s_b + bias[n]
//
// R6 post-mortem: 48-49us for the N=1024 GEMMs across EVERY schedule variant
// (drain/counted vmcnt, depth 1/3, 1-2 waves/SIMD) -> the invariant was all
// waves on a CU in ONE block meeting the SAME barrier: zero TLP; per-iter
// latency (ds_read + LDS pipe + barrier skew) paid serially by the whole CU.
//
// This version: 64x64 tile, 256 threads, 4 waves (2x2 of 32x32, acc[2][2] =
// 16 regs). N=1024 grids become 1024 blocks = 4 INDEPENDENT blocks/CU: one
// block's barrier stall overlaps three others' MFMA. LDS 4 buffers x 8KB =
// 32KB -> 4 blocks/CU fit. Depth-3 counted-vmcnt pipeline kept (harmless).
// XOR slot swizzle unchanged (row geometry identical -> still conflict-free).
// ---------------------------------------------------------------------------
__global__ __launch_bounds__(256, 4) void gemm_i8_kernel(
    const signed char* __restrict__ A, const signed char* __restrict__ Bw,
    const float* __restrict__ biasq,
    const float* __restrict__ amax_a, float div_a,
    const float* __restrict__ amax_b,
    const int* __restrict__ rowsum,           // nullable: adds 128*rowsum[n]
    float* __restrict__ C, int M, int N, int K,
    float* __restrict__ amax_out, int relu_amax, int mode) {
  __shared__ signed char Asm[4][4096];  // 64 rows x 64B, K-contiguous
  __shared__ signed char Bsm[4][4096];
  __shared__ float redm[4];
  const int t = threadIdx.x;
  // XCD-aware swizzle (gridDim.y % 8 == 0): xcd gets M-band [xcd*gy/8 .. )
  int bx, by;
  {
    int lin = blockIdx.y * gridDim.x + blockIdx.x;
    if ((gridDim.y & 7) == 0) {
      int xcd = lin & 7, j = lin >> 3;
      bx = j % gridDim.x;
      by = (gridDim.y >> 3) * xcd + j / gridDim.x;
    } else { bx = blockIdx.x; by = blockIdx.y; }
  }
  const int m0 = by * 64, n0 = bx * 64;
  const int w = t >> 6, lane = t & 63;
  const int fr = lane & 15, quad = lane >> 4;
  const int wm = w >> 1, wn = w & 1;    // 2x2: wave owns rows wm*32, cols wn*32
  const int r0 = t >> 2;                // staging row 0..63 (256 threads)
  // Swizzle: LDS(row r, slot s) holds global(row r, slot s ^ ((r>>1)&3)).
  const int csrc = (((t & 3) ^ ((t >> 3) & 3)) << 4);
  // Read side: LDS slot = quad ^ ((fr>>1)&3) (same involution; (rr>>1)&3
  // == (fr>>1)&3 because rr = 16k + fr).
  const int sx = ((quad ^ ((fr >> 1) & 3)) << 4);

  int4v acc[2][2];
#pragma unroll
  for (int r = 0; r < 2; r++)
#pragma unroll
    for (int c = 0; c < 2; c++) acc[r][c] = (int4v){0, 0, 0, 0};

  const long arow = (long)(m0 + r0) * K + csrc;
  const long brow = (long)(n0 + r0) * K + csrc;

  auto stage = [&](int buf, int kt) {
    const int kk = kt << 6;
    gl2lds16(A + arow + kk, Asm[buf] + t * 16);
    gl2lds16(Bw + brow + kk, Bsm[buf] + t * 16);
  };
  auto compute = [&](int buf) {
    int4v af[2], bf[2];
#pragma unroll
    for (int r = 0; r < 2; r++)
      af[r] = *(const int4v*)(Asm[buf] + (wm * 32 + r * 16 + fr) * 64 + sx);
#pragma unroll
    for (int c = 0; c < 2; c++)
      bf[c] = *(const int4v*)(Bsm[buf] + (wn * 32 + c * 16 + fr) * 64 + sx);
#pragma unroll
    for (int r = 0; r < 2; r++)
#pragma unroll
      for (int c = 0; c < 2; c++)
        acc[r][c] = __builtin_amdgcn_mfma_i32_16x16x64_i8(af[r], bf[c], acc[r][c], 0, 0, 0);
  };

  const int nt = K >> 6;  // 16 (K=1024) or 64 (K=4096); always >= 3
  stage(0, 0);
  stage(1, 1);
  stage(2, 2);
  for (int kt = 0; kt < nt; ++kt) {
    const int rem = nt - 1 - kt;  // tiles beyond current still needed
    if (rem >= 2)      { __asm__ volatile("s_waitcnt vmcnt(4)" ::: "memory"); }
    else if (rem == 1) { __asm__ volatile("s_waitcnt vmcnt(2)" ::: "memory"); }
    else               { __asm__ volatile("s_waitcnt vmcnt(0)" ::: "memory"); }
    RAW_BARRIER();     // tile kt resident for ALL waves; prev readers of (kt+3)&3 done
    if (kt + 3 < nt) stage((kt + 3) & 3, kt + 3);
    compute(kt & 3);
  }

  // --- epilogue ---
  const int seg = (mode == 1) ? (n0 >> 10) : 0;
  const float s_a = fmaxf(amax_a[0] / div_a, 1e-8f);
  const float s_b = fmaxf(amax_b[seg] / 127.f, 1e-8f);
  const float s = s_a * s_b;
  float lmax = 0.f;
#pragma unroll
  for (int r = 0; r < 2; r++) {
    int rbase = m0 + wm * 32 + r * 16 + quad * 4;
#pragma unroll
    for (int c = 0; c < 2; c++) {
      int col = n0 + wn * 32 + c * 16 + fr;
      int corr = rowsum ? (rowsum[col] << 7) : 0;
      float bi = biasq[col];
      if (mode == 1) {
        // segment-local fp32 [B,H,S,D] write
        int h = (col >> 6) & 15, dd = col & 63;
        float* cbase = C + (long)seg * ((long)TB_ROWS * TB_E);
#pragma unroll
        for (int g = 0; g < 4; g++) {
          int m = rbase + g;
          int b = m >> 10, sdx = m & 1023;
          float o = (float)acc[r][c][g] * s + bi;
          lmax = fmaxf(lmax, fabsf(o));
          cbase[((((long)b * TB_H + h) * TB_S) + sdx) * TB_D + dd] = o;
        }
      } else {
#pragma unroll
        for (int g = 0; g < 4; g++) {
          float o = (float)(acc[r][c][g] + corr) * s + bi;
          lmax = fmaxf(lmax, relu_amax ? fmaxf(o, 0.f) : fabsf(o));
          C[(long)(rbase + g) * N + col] = o;
        }
      }
    }
  }
#pragma unroll
  for (int o = 32; o; o >>= 1) lmax = fmaxf(lmax, __shfl_down(lmax, o, 64));
  if (!lane) redm[w] = lmax;
  __syncthreads();
  if (t == 0)
    atomicMaxF(amax_out + seg, fmaxf(fmaxf(redm[0], redm[1]), fmaxf(redm[2], redm[3])));
}

// ---------------------------------------------------------------------------
// v quant + transpose: fp32 [B,H,S,D] -> i8 blocked [BH][jb][D][64]
// ---------------------------------------------------------------------------
__global__ __launch_bounds__(256) void quant8_vb_kernel(const float* __restrict__ v,
                                                        const float* __restrict__ amax_p,
                                                        signed char* __restrict__ v8b) {
  __shared__ signed char tile[64][80];  // [d][s], stride 80
  const int bh = blockIdx.x;
  const int jb = blockIdx.y;
  const int s0 = jb * 64;
  const int t = threadIdx.x;
  const float scale = fmaxf(amax_p[0] / 127.f, 1e-8f);
#pragma unroll
  for (int it = 0; it < 4; it++) {
    int idx = t + it * 256;           // 0..1023 float4 slots
    int r = idx >> 4, c4 = (idx & 15) * 4;
    float4 vv = *(const float4*)(v + ((long)bh * TB_S + s0 + r) * TB_D + c4);
    tile[c4 + 0][r] = (signed char)(int)fminf(fmaxf(rintf(vv.x / scale), -128.f), 127.f);
    tile[c4 + 1][r] = (signed char)(int)fminf(fmaxf(rintf(vv.y / scale), -128.f), 127.f);
    tile[c4 + 2][r] = (signed char)(int)fminf(fmaxf(rintf(vv.z / scale), -128.f), 127.f);
    tile[c4 + 3][r] = (signed char)(int)fminf(fmaxf(rintf(vv.w / scale), -128.f), 127.f);
  }
  __syncthreads();
  int d = t >> 2, sb = (t & 3) * 16;
  int4v o = *(const int4v*)&tile[d][sb];
  *(int4v*)(v8b + (((long)bh * 16 + jb) * 64 + d) * 64 + sb) = o;
}

// ---------------------------------------------------------------------------
// Attention pass A: per-row signed int max of scores -> irowmax; global int
// absmax -> imax_out. q8/k8 in [B,H,S,D]; wave loads are 1KB contiguous.
// D[m=j][n=i]: lane (fr,quad) holds i = i0+fr, j = j0 + quad*4 + g.
// ---------------------------------------------------------------------------
__global__ __launch_bounds__(256) void attn_rowmax_kernel(const signed char* __restrict__ q8,
                                                          const signed char* __restrict__ k8,
                                                          int* __restrict__ irowmax,
                                                          int* __restrict__ imax_out) {
  const int bh = blockIdx.x;
  const int t = threadIdx.x, w = t >> 6, lane = t & 63;
  const int fr = lane & 15, quad = lane >> 4;
  const int i0 = blockIdx.y * 64 + w * 16;
  const long base = (long)bh * TB_S;
  int4v qf = *(const int4v*)(q8 + (base + i0 + fr) * 64 + quad * 16);
  int mx = -2147483647, mn = 2147483647;
  for (int j0 = 0; j0 < TB_S; j0 += 16) {
    int4v kf = *(const int4v*)(k8 + (base + j0 + fr) * 64 + quad * 16);
    int4v sc = __builtin_amdgcn_mfma_i32_16x16x64_i8(kf, qf, (int4v){0, 0, 0, 0}, 0, 0, 0);
    mx = max(mx, max(max(sc[0], sc[1]), max(sc[2], sc[3])));
    mn = min(mn, min(min(sc[0], sc[1]), min(sc[2], sc[3])));
  }
  mx = max(mx, __shfl_xor(mx, 16, 64));
  mx = max(mx, __shfl_xor(mx, 32, 64));
  mn = min(mn, __shfl_xor(mn, 16, 64));
  mn = min(mn, __shfl_xor(mn, 32, 64));
  if (quad == 0) irowmax[(long)bh * TB_S + i0 + fr] = mx;
  int gm = max(mx, -mn);
#pragma unroll
  for (int o = 32; o; o >>= 1) gm = max(gm, __shfl_down(gm, o, 64));
  __shared__ int sm[4];
  if (!lane) sm[w] = gm;
  __syncthreads();
  if (t == 0) atomicMax(imax_out, max(max(sm[0], sm[1]), max(sm[2], sm[3])));
}

// ---------------------------------------------------------------------------
// Attention pass B: l = sum exp2((qv - qmax)*aa) per row. rowl <- l;
// amax_attn <- max(1/l). NOTE: the qv clamps to [-128,127] are mathematically
// dead (|sc| <= imax -> |sc*c1| <= 127 in both s_sc branches) and are dropped
// here AND in pass C identically, so codes stay consistent.
// ---------------------------------------------------------------------------
__global__ __launch_bounds__(256) void attn_rowsum_kernel(
    const signed char* __restrict__ q8, const signed char* __restrict__ k8,
    const int* __restrict__ irowmax, const int* __restrict__ imax_p,
    const float* __restrict__ amax_q, const float* __restrict__ amax_k,
    float* __restrict__ rowl, float* __restrict__ amax_attn) {
  const int bh = blockIdx.x;
  const int t = threadIdx.x, w = t >> 6, lane = t & 63;
  const int fr = lane & 15, quad = lane >> 4;
  const int i0 = blockIdx.y * 64 + w * 16;
  const float s_q = fmaxf(amax_q[0] * 0.125f / 127.f, 1e-8f);
  const float s_k = fmaxf(amax_k[0] / 127.f, 1e-8f);
  const float sqk = s_q * s_k;
  const float s_sc = fmaxf((float)imax_p[0] * sqk / 127.f, 1e-8f);
  const float c1 = sqk / s_sc;
  const float aa = s_sc * 1.44269504088896340736f;
  const long base = (long)bh * TB_S;
  int4v qf = *(const int4v*)(q8 + (base + i0 + fr) * 64 + quad * 16);
  const int imr = irowmax[base + i0 + fr];
  const float qmax = fminf(fmaxf(rintf((float)imr * c1), -128.f), 127.f);
  const float qa = qmax * aa;
  float l = 0.f;
  for (int j0 = 0; j0 < TB_S; j0 += 16) {
    int4v kf = *(const int4v*)(k8 + (base + j0 + fr) * 64 + quad * 16);
    int4v sc = __builtin_amdgcn_mfma_i32_16x16x64_i8(kf, qf, (int4v){0, 0, 0, 0}, 0, 0, 0);
#pragma unroll
    for (int g = 0; g < 4; g++) {
      float qv = rintf((float)sc[g] * c1);   // clamps dead: |sc*c1| <= 127
      l += fast_exp2(fmaf(qv, aa, -qa));
    }
  }
  l += __shfl_xor(l, 16, 64);
  l += __shfl_xor(l, 32, 64);
  if (quad == 0) rowl[base + i0 + fr] = l;
  float inv = 1.f / l;                        // row max of softmax = 1/l
#pragma unroll
  for (int o = 32; o; o >>= 1) inv = fmaxf(inv, __shfl_down(inv, o, 64));
  __shared__ float smf[4];
  if (!lane) smf[w] = inv;
  __syncthreads();
  if (t == 0) atomicMaxF(amax_attn, fmaxf(fmaxf(smf[0], smf[1]), fmaxf(smf[2], smf[3])));
}

// ---------------------------------------------------------------------------
// Attention pass C: recompute scores (identical expr -> identical codes),
// attn code via magic-constant round (clamps dead, see R6); per-wave LDS
// transpose; PV MFMA on blocked v8b. ctx fp32 [B,S,H,D] + fused absmax.
//
// R6 post-mortem: VALU trim moved VALUBusy 54->40 but not time -> the kernel
// is CHAIN-latency-bound (QK MFMA -> exp VALU -> LDS write -> LDS read -> PV
// MFMA serial per tile). This version: 2-deep j0 pipeline with double-buffered
// per-wave latt: at iter jt, QK codes for tile jt+1 are computed into regs
// (independent) while PV for tile jt consumes codes written LAST iteration.
// PV's MFMAs issue while QK's exp chain waits on its MFMA results -> the two
// latency chains hide under each other. latt is wave-private; in-order DS
// gives read-before-write; no barriers.
// ---------------------------------------------------------------------------
__global__ __launch_bounds__(256) void attn_pv_kernel(
    const signed char* __restrict__ q8, const signed char* __restrict__ k8,
    const signed char* __restrict__ v8b,
    const int* __restrict__ irowmax, const int* __restrict__ imax_p,
    const float* __restrict__ amax_q, const float* __restrict__ amax_k,
    const float* __restrict__ amax_v, const float* __restrict__ amax_attn,
    const float* __restrict__ rowl,
    float* __restrict__ ctx, float* __restrict__ amax_ctx) {
  __shared__ signed char latt[2][4][16][80];  // [buf][wave][i-rel][j-byte], stride 80
  const int bh = blockIdx.x, b = bh >> 4, h = bh & 15;
  const int t = threadIdx.x, w = t >> 6, lane = t & 63;
  const int fr = lane & 15, quad = lane >> 4;
  const int i0 = blockIdx.y * 64 + w * 16;
  const float s_q = fmaxf(amax_q[0] * 0.125f / 127.f, 1e-8f);
  const float s_k = fmaxf(amax_k[0] / 127.f, 1e-8f);
  const float sqk = s_q * s_k;
  const float s_sc = fmaxf((float)imax_p[0] * sqk / 127.f, 1e-8f);
  const float c1 = sqk / s_sc;
  const float aa = s_sc * 1.44269504088896340736f;
  const float s_v = fmaxf(amax_v[0] / 127.f, 1e-8f);
  const float s_at = fmaxf(amax_attn[0] / 127.f, 1e-8f);
  const long base = (long)bh * TB_S;
  int4v qf = *(const int4v*)(q8 + (base + i0 + fr) * 64 + quad * 16);
  const int imr = irowmax[base + i0 + fr];
  const float qmax = fminf(fmaxf(rintf((float)imr * c1), -128.f), 127.f);
  const float bexp = qmax * aa;
  const float li = rowl[base + i0 + fr];
  const float invls = 1.f / (li * s_at);             // one exact div per row
  int4v accv[4];
#pragma unroll
  for (int dtile = 0; dtile < 4; dtile++) accv[dtile] = (int4v){0, 0, 0, 0};

  // QK^T + quantize codes for one 64-wide j tile -> 4 packed ints (regs)
  int pk[4];
  auto qk4 = [&](int j0) {
#pragma unroll
    for (int tt = 0; tt < 4; tt++) {
      int4v kf = *(const int4v*)(k8 + (base + j0 + tt * 16 + fr) * 64 + quad * 16);
      int4v sc = __builtin_amdgcn_mfma_i32_16x16x64_i8(kf, qf, (int4v){0, 0, 0, 0}, 0, 0, 0);
      int packed = 0;
#pragma unroll
      for (int g = 0; g < 4; g++) {
        float qv = rintf((float)sc[g] * c1);            // clamps dead
        float e = fast_exp2(fmaf(qv, aa, -bexp));       // e in [0,1]
        float f = fmaf(e, invls, 12582912.f);           // rne(e*invls) in mantissa
        packed |= (__float_as_int(f) & 255) << (g * 8); // code in [0,127]
      }
      pk[tt] = packed;
    }
  };

  // prologue: codes for tile 0 -> latt[0]
  qk4(0);
#pragma unroll
  for (int tt = 0; tt < 4; tt++)
    *(int*)&latt[0][w][fr][tt * 16 + quad * 4] = pk[tt];

  const int njt = TB_S / 64;   // 16
  for (int jt = 0; jt < njt; ++jt) {
    const int cur = jt & 1;
    if (jt + 1 < njt) qk4((jt + 1) * 64);   // tile jt+1 codes, independent of PV below
    LGKM0();   // writes into latt[cur] (issued last iter / prologue) complete
    int4v af = *(const int4v*)&latt[cur][w][fr][quad * 16];
    const signed char* vbase = v8b + (((long)bh * 16 + jt) * 64) * 64;
#pragma unroll
    for (int dtile = 0; dtile < 4; dtile++) {
      int4v vf = *(const int4v*)(vbase + (dtile * 16 + fr) * 64 + quad * 16);
      accv[dtile] = __builtin_amdgcn_mfma_i32_16x16x64_i8(af, vf, accv[dtile], 0, 0, 0);
    }
    if (jt + 1 < njt) {
      CMEMBAR(); // in-order DS: this wave's af read precedes these writes
#pragma unroll
      for (int tt = 0; tt < 4; tt++)
        *(int*)&latt[cur ^ 1][w][fr][tt * 16 + quad * 4] = pk[tt];
    }
  }
  const float sav = s_at * s_v;
  float cmax = 0.f;
#pragma unroll
  for (int dtile = 0; dtile < 4; dtile++) {
#pragma unroll
    for (int g = 0; g < 4; g++) {
      float val = (float)accv[dtile][g] * sav;
      cmax = fmaxf(cmax, fabsf(val));
      int irow = i0 + quad * 4 + g;
      ctx[(((long)(b * TB_S + irow)) * TB_H + h) * TB_D + dtile * 16 + fr] = val;
    }
  }
#pragma unroll
  for (int o = 32; o; o >>= 1) cmax = fmaxf(cmax, __shfl_down(cmax, o, 64));
  __shared__ float smf[4];
  if (!lane) smf[w] = cmax;
  __syncthreads();
  if (t == 0) atomicMaxF(amax_ctx, fmaxf(fmaxf(smf[0], smf[1]), fmaxf(smf[2], smf[3])));
}

// ---------------------------------------------------------------------------
// h = LayerNorm(dequant(a8) + fakequant(braw)); fused output absmax.
// Wave-per-row (4 rows/block), single-pass sum+sumsq (var = E[x^2]-mu^2),
// no block barriers in the main path.
// ---------------------------------------------------------------------------
__global__ __launch_bounds__(256) void resid_ln_kernel(const signed char* __restrict__ a8,
                                                       const float* __restrict__ amax_a,
                                                       const float* __restrict__ braw,
                                                       const float* __restrict__ amax_b,
                                                       float* __restrict__ outp,
                                                       float* __restrict__ amax_out) {
  const int t = threadIdx.x, w = t >> 6, lane = t & 63;
  const int row = blockIdx.x * 4 + w;
  const float sa = fmaxf(amax_a[0] / 127.f, 1e-8f);
  const float sb = fmaxf(amax_b[0] / 127.f, 1e-8f);
  const long base = (long)row * TB_E;
  float v[16];
  float s = 0.f, q = 0.f;
#pragma unroll
  for (int j = 0; j < 4; j++) {
    char4 a = ((const char4*)(a8 + base))[j * 64 + lane];
    float4 bv = *(const float4*)(braw + base + j * 256 + lane * 4);
    float x0 = (float)a.x * sa + fminf(fmaxf(rintf(bv.x / sb), -128.f), 127.f) * sb;
    float x1 = (float)a.y * sa + fminf(fmaxf(rintf(bv.y / sb), -128.f), 127.f) * sb;
    float x2 = (float)a.z * sa + fminf(fmaxf(rintf(bv.z / sb), -128.f), 127.f) * sb;
    float x3 = (float)a.w * sa + fminf(fmaxf(rintf(bv.w / sb), -128.f), 127.f) * sb;
    v[j * 4 + 0] = x0; v[j * 4 + 1] = x1; v[j * 4 + 2] = x2; v[j * 4 + 3] = x3;
    s += (x0 + x1) + (x2 + x3);
    q += (x0 * x0 + x1 * x1) + (x2 * x2 + x3 * x3);
  }
  // dual wave-allreduce (independent chains -> ILP overlap)
#pragma unroll
  for (int o = 32; o; o >>= 1) {
    s += __shfl_xor(s, o, 64);
    q += __shfl_xor(q, o, 64);
  }
  const float mu = s * (1.f / TB_E);
  const float var = fmaxf(q * (1.f / TB_E) - mu * mu, 0.f);
  const float rs = 1.f / sqrtf(var + 1e-5f);
  float lm = 0.f;
#pragma unroll
  for (int j = 0; j < 4; j++) {
    float4 o4;
    o4.x = (v[j * 4 + 0] - mu) * rs;
    o4.y = (v[j * 4 + 1] - mu) * rs;
    o4.z = (v[j * 4 + 2] - mu) * rs;
    o4.w = (v[j * 4 + 3] - mu) * rs;
    *(float4*)(outp + base + j * 256 + lane * 4) = o4;
    lm = fmaxf(lm, fmaxf(fmaxf(fabsf(o4.x), fabsf(o4.y)), fmaxf(fabsf(o4.z), fabsf(o4.w))));
  }
#pragma unroll
  for (int o = 32; o; o >>= 1) lm = fmaxf(lm, __shfl_down(lm, o, 64));
  __shared__ float redm[4];
  if (!lane) redm[w] = lm;
  __syncthreads();
  if (t == 0) atomicMaxF(amax_out, fmaxf(fmaxf(redm[0], redm[1]), fmaxf(redm[2], redm[3])));
}

// ---------------------------------------------------------------------------
// Host side
// ---------------------------------------------------------------------------
#define SL_X 0
#define SL_WQ 1
#define SL_WK 2
#define SL_WV 3
#define SL_WO 4
#define SL_W1 5
#define SL_W2 6
#define SL_BQ 7
#define SL_BK 8
#define SL_BV 9
#define SL_BO 10
#define SL_B1 11
#define SL_B2 12
#define SL_Q 13   // SL_K = 14, SL_V = 15 must stay consecutive (QKV epilogue)
#define SL_K 14
#define SL_V 15
#define SL_SCI 16     // int imax of scores
#define SL_ATTN 17
#define SL_CTX 18
#define SL_AO 19
#define SL_H 20
#define SL_RELU 21
#define SL_M2 22
#define SL_DUMMY 23

static inline int nblocks(long n) {
  long b = (n + 255) / 256;
  return (int)(b > 2048 ? 2048 : b);
}

extern "C" void kernel_launch(void* const* d_in, const int* in_sizes, int n_in,
                              void* d_out, int out_size, void* d_ws, size_t ws_size,
                              hipStream_t stream) {
  const float* x  = (const float*)d_in[0];
  const float* Wq = (const float*)d_in[1];
  const float* bq = (const float*)d_in[2];
  const float* Wk = (const float*)d_in[3];
  const float* bk = (const float*)d_in[4];
  const float* Wv = (const float*)d_in[5];
  const float* bv = (const float*)d_in[6];
  const float* Wo = (const float*)d_in[7];
  const float* bo = (const float*)d_in[8];
  const float* W1 = (const float*)d_in[9];
  const float* b1 = (const float*)d_in[10];
  const float* W2 = (const float*)d_in[11];
  const float* b2 = (const float*)d_in[12];
  float* ws = (float*)d_ws;
  float* out = (float*)d_out;

  const long SZ_XE = (long)TB_ROWS * TB_E;      // 4,194,304
  const long SZ_W  = (long)TB_E * TB_E;         // 1,048,576
  const long SZ_M1 = (long)TB_ROWS * TB_MLP;    // 16,777,216

  // float-offset layout
  const long OFF_QBQ = 1024, OFF_QBK = 2048, OFF_QBV = 3072, OFF_QBO = 4096;
  const long OFF_QB1 = 5120, OFF_QB2 = 9216;
  const long OFF_RSUM = 10240;                  // int32[1024]
  const long OFF_Q  = 65536;                    // fp32 q [B,H,S,D], later ctx
  const long OFF_K  = OFF_Q + SZ_XE;            // fp32 k [B,H,S,D], later attn_out
  const long OFF_V  = OFF_K + SZ_XE;            // fp32 v [B,H,S,D], later h
  const long OFF_M2 = OFF_V + SZ_XE;            // fp32 m2
  const long OFF_IRM = OFF_M2 + SZ_XE;          // int irowmax [65536]
  const long OFF_ROWL = OFF_IRM + 65536;
  const long OFF_M1 = OFF_ROWL + 65536;         // fp32 m1 (64MB)
  const long OFF_I8 = OFF_M1 + SZ_M1;           // i8 region start (float offset)

  float* qbuf = ws + OFF_Q;  float* kbuf = ws + OFF_K;  float* vbuf = ws + OFF_V;
  float* m2   = ws + OFF_M2;
  int*   irowmax = (int*)(ws + OFF_IRM);
  float* rowl = ws + OFF_ROWL;
  float* m1 = ws + OFF_M1;
  float* ctx = qbuf;        // reuse q (q8 codes already extracted)
  float* attn_out = kbuf;   // reuse k
  float* hbuf = vbuf;       // reuse v
  float* qbq_ = ws + OFF_QBQ; float* qbk_ = ws + OFF_QBK;
  float* qbv_ = ws + OFF_QBV; float* qbo_ = ws + OFF_QBO;
  float* qb1_ = ws + OFF_QB1; float* qb2_ = ws + OFF_QB2;
  int* rsum = (int*)(ws + OFF_RSUM);
  int* imax = (int*)(ws + SL_SCI);

  // i8 code buffers (byte pointers)
  signed char* i8base = (signed char*)(ws + OFF_I8);
  signed char* qx8  = i8base;                   // 4096x1024 [rows,E]
  signed char* wq8  = qx8 + SZ_XE;              // 1024x1024  (wq8,wk8,wv8 contiguous for QKV fusion)
  signed char* wk8  = wq8 + SZ_W;
  signed char* wv8  = wk8 + SZ_W;
  signed char* wo8  = wv8 + SZ_W;
  signed char* w18  = wo8 + SZ_W;               // 4096x1024
  signed char* w28  = w18 + SZ_XE;              // 1024x4096
  signed char* ctx8 = w28 + SZ_XE;              // 4096x1024
  signed char* m08  = ctx8 + SZ_XE;             // 4096x1024
  signed char* m18  = m08 + SZ_XE;              // 4096x4096 (relu codes - 128)
  signed char* q8   = m18 + SZ_M1;              // [B,H,S,D]
  signed char* k8   = q8 + SZ_XE;               // [B,H,S,D]
  signed char* v8b  = k8 + SZ_XE;               // [BH][16][64][64]

  hipMemsetAsync(ws, 0, 4096, stream);  // zero scalar slots

  // --- absmax of all 13 inputs (1 dispatch) ---
  AMBatch am;
  am.d[0]  = {x,  SZ_XE/4, SL_X};
  am.d[1]  = {Wq, SZ_W/4,  SL_WQ};
  am.d[2]  = {Wk, SZ_W/4,  SL_WK};
  am.d[3]  = {Wv, SZ_W/4,  SL_WV};
  am.d[4]  = {Wo, SZ_W/4,  SL_WO};
  am.d[5]  = {W1, SZ_XE/4, SL_W1};
  am.d[6]  = {W2, SZ_XE/4, SL_W2};
  am.d[7]  = {bq, 256,     SL_BQ};
  am.d[8]  = {bk, 256,     SL_BK};
  am.d[9]  = {bv, 256,     SL_BV};
  am.d[10] = {bo, 256,     SL_BO};
  am.d[11] = {b1, 1024,    SL_B1};
  am.d[12] = {b2, 256,     SL_B2};
  absmax_multi_kernel<<<dim3(64, 13), 256, 0, stream>>>(am, ws);

  // --- quantize x + 6 weights to i8 codes (1 dispatch); biases (1 dispatch) ---
  QMBatch qm;
  qm.d[0] = {x,  qx8, SZ_XE/4, SL_X,  -128.f};
  qm.d[1] = {Wq, wq8, SZ_W/4,  SL_WQ, -127.f};
  qm.d[2] = {Wk, wk8, SZ_W/4,  SL_WK, -127.f};
  qm.d[3] = {Wv, wv8, SZ_W/4,  SL_WV, -127.f};
  qm.d[4] = {W1, w18, SZ_XE/4, SL_W1, -127.f};
  qm.d[5] = {W2, w28, SZ_XE/4, SL_W2, -127.f};
  qm.d[6] = {Wo, wo8, SZ_W/4,  SL_WO, -127.f};
  quant8_multi_kernel<<<dim3(64, 7), 256, 0, stream>>>(qm, ws);
  rowsum_i8_kernel<<<TB_E, 256, 0, stream>>>(w28, rsum, TB_MLP);
  BBatch bb;
  bb.d[0] = {bq, qbq_, 256,  SL_BQ};
  bb.d[1] = {bk, qbk_, 256,  SL_BK};
  bb.d[2] = {bv, qbv_, 256,  SL_BV};
  bb.d[3] = {bo, qbo_, 256,  SL_BO};
  bb.d[4] = {b1, qb1_, 1024, SL_B1};
  bb.d[5] = {b2, qb2_, 256,  SL_B2};
  bias_quant_multi_kernel<<<dim3(4, 6), 256, 0, stream>>>(bb, ws);

  // --- fused QKV in-projection (int8 MFMA, exact): N=3072, writes [B,H,S,D] fp32 ---
  gemm_i8_kernel<<<dim3(3*TB_E/64, TB_ROWS/64), 256, 0, stream>>>(
      qx8, wq8, qbq_, ws + SL_X, 127.f, ws + SL_WQ, nullptr, qbuf,
      TB_ROWS, 3*TB_E, TB_E, ws + SL_Q, 0, 1);

  // --- quantize q (pre=1/8), k (linear, layouts already [B,H,S,D]); v blocked ---
  quant8_kernel<<<2048, 256, 0, stream>>>(qbuf, q8, SZ_XE/4, ws + SL_Q, 0.125f, -128.f);
  quant8_kernel<<<2048, 256, 0, stream>>>(kbuf, k8, SZ_XE/4, ws + SL_K, 1.f, -128.f);
  quant8_vb_kernel<<<dim3(TB_B*TB_H, TB_S/64), 256, 0, stream>>>(vbuf, ws + SL_V, v8b);

  // --- attention (i8 MFMA, 3 passes) ---
  attn_rowmax_kernel<<<dim3(TB_B*TB_H, TB_S/64), 256, 0, stream>>>(q8, k8, irowmax, imax);
  attn_rowsum_kernel<<<dim3(TB_B*TB_H, TB_S/64), 256, 0, stream>>>(
      q8, k8, irowmax, imax, ws + SL_Q, ws + SL_K, rowl, ws + SL_ATTN);
  attn_pv_kernel<<<dim3(TB_B*TB_H, TB_S/64), 256, 0, stream>>>(
      q8, k8, v8b, irowmax, imax, ws + SL_Q, ws + SL_K, ws + SL_V, ws + SL_ATTN,
      rowl, ctx, ws + SL_CTX);

  // --- out projection ---
  quant8_kernel<<<2048, 256, 0, stream>>>(ctx, ctx8, SZ_XE/4, ws + SL_CTX, 1.f, -128.f);
  gemm_i8_kernel<<<dim3(TB_E/64, TB_ROWS/64), 256, 0, stream>>>(
      ctx8, wo8, qbo_, ws + SL_CTX, 127.f, ws + SL_WO, nullptr, attn_out,
      TB_ROWS, TB_E, TB_E, ws + SL_AO, 0, 0);

  // --- residual + LN (fused h absmax) ---
  resid_ln_kernel<<<TB_ROWS/4, 256, 0, stream>>>(qx8, ws + SL_X, attn_out, ws + SL_AO, hbuf, ws + SL_H);

  // --- MLP ---
  quant8_kernel<<<2048, 256, 0, stream>>>(hbuf, m08, SZ_XE/4, ws + SL_H, 1.f, -128.f);
  gemm_i8_kernel<<<dim3(TB_MLP/64, TB_ROWS/64), 256, 0, stream>>>(
      m08, w18, qb1_, ws + SL_H, 127.f, ws + SL_W1, nullptr, m1,
      TB_ROWS, TB_MLP, TB_E, ws + SL_RELU, 1, 0);
  relu_quant8_kernel<<<nblocks(SZ_M1/4), 256, 0, stream>>>(m1, m18, SZ_M1/4, ws + SL_RELU);
  gemm_i8_kernel<<<dim3(TB_E/64, TB_ROWS/64), 256, 0, stream>>>(
      m18, w28, qb2_, ws + SL_RELU, 255.f, ws + SL_W2, rsum, m2,
      TB_ROWS, TB_E, TB_MLP, ws + SL_M2, 0, 0);

  // --- final residual + LN ---
  resid_ln_kernel<<<TB_ROWS/4, 256, 0, stream>>>(m08, ws + SL_H, m2, ws + SL_M2, out, ws + SL_DUMMY);
}

// Round 8
// 485.903 us; speedup vs baseline: 1.0819x; 1.0819x over previous
//
#include <hip/hip_runtime.h>
#include <cstdint>
#include <cstddef>

// Problem constants
#define TB_B 4
#define TB_S 1024
#define TB_E 1024
#define TB_H 16
#define TB_D 64
#define TB_MLP 4096
#define TB_ROWS (TB_B * TB_S)   // 4096

typedef int int4v __attribute__((ext_vector_type(4)));

#define LGKM0() __asm__ volatile("s_waitcnt lgkmcnt(0)" ::: "memory")
#define CMEMBAR() __asm__ volatile("" ::: "memory")
// raw barrier with compiler memory fences (no vmcnt drain, unlike __syncthreads)
#define RAW_BARRIER() do { __asm__ volatile("" ::: "memory"); \
  __builtin_amdgcn_s_barrier(); __asm__ volatile("" ::: "memory"); } while (0)

static __device__ __forceinline__ void atomicMaxF(float* addr, float v) {
  // valid for non-negative floats: IEEE bit pattern is monotonic
  atomicMax(reinterpret_cast<unsigned int*>(addr), __float_as_uint(v));
}

static __device__ __forceinline__ float fast_exp2(float x) {
#if __has_builtin(__builtin_amdgcn_exp2f)
  return __builtin_amdgcn_exp2f(x);
#else
  return exp2f(x);
#endif
}

// async global->LDS, 16 bytes per lane. LDS dest must be wave-uniform base + lane*16.
static __device__ __forceinline__ void gl2lds16(const void* g, void* l) {
  __builtin_amdgcn_global_load_lds(
      (const __attribute__((address_space(1))) void*)g,
      (__attribute__((address_space(3))) void*)l, 16, 0, 0);
}

// ---------------------------------------------------------------------------
// multi-tensor absmax: one dispatch for all 13 input tensors
// ---------------------------------------------------------------------------
struct AMDesc { const float* p; long n4; int slot; };
struct AMBatch { AMDesc d[13]; };
__global__ __launch_bounds__(256) void absmax_multi_kernel(AMBatch bt, float* ws) {
  AMDesc d = bt.d[blockIdx.y];
  float m = 0.f;
  long stride = (long)gridDim.x * 256;
  for (long i = (long)blockIdx.x * 256 + threadIdx.x; i < d.n4; i += stride) {
    float4 v = ((const float4*)d.p)[i];
    m = fmaxf(m, fmaxf(fmaxf(fabsf(v.x), fabsf(v.y)), fmaxf(fabsf(v.z), fabsf(v.w))));
  }
#pragma unroll
  for (int o = 32; o; o >>= 1) m = fmaxf(m, __shfl_down(m, o, 64));
  __shared__ float sm[4];
  if (!(threadIdx.x & 63)) sm[threadIdx.x >> 6] = m;
  __syncthreads();
  if (threadIdx.x == 0)
    atomicMaxF(ws + d.slot, fmaxf(fmaxf(sm[0], sm[1]), fmaxf(sm[2], sm[3])));
}

// multi-tensor fake-quant -> i8 codes (x + 6 weights)
struct QMDesc { const float* in; signed char* out; long n4; int slot; float qmin; };
struct QMBatch { QMDesc d[7]; };
__global__ __launch_bounds__(256) void quant8_multi_kernel(QMBatch bt, const float* ws) {
  QMDesc d = bt.d[blockIdx.y];
  float scale = fmaxf(ws[d.slot] / 127.f, 1e-8f);
  long stride = (long)gridDim.x * 256;
  for (long i = (long)blockIdx.x * 256 + threadIdx.x; i < d.n4; i += stride) {
    float4 v = ((const float4*)d.in)[i];
    char4 o;
    o.x = (signed char)(int)fminf(fmaxf(rintf(v.x / scale), d.qmin), 127.f);
    o.y = (signed char)(int)fminf(fmaxf(rintf(v.y / scale), d.qmin), 127.f);
    o.z = (signed char)(int)fminf(fmaxf(rintf(v.z / scale), d.qmin), 127.f);
    o.w = (signed char)(int)fminf(fmaxf(rintf(v.w / scale), d.qmin), 127.f);
    ((char4*)d.out)[i] = o;
  }
}

// multi-tensor bias fake-quant -> fp32
struct BDesc { const float* in; float* out; int n4; int slot; };
struct BBatch { BDesc d[6]; };
__global__ __launch_bounds__(256) void bias_quant_multi_kernel(BBatch bt, const float* ws) {
  BDesc d = bt.d[blockIdx.y];
  float scale = fmaxf(ws[d.slot] / 127.f, 1e-8f);
  int i = blockIdx.x * 256 + threadIdx.x;
  if (i < d.n4) {
    float4 v = ((const float4*)d.in)[i];
    float4 o;
    o.x = fminf(fmaxf(rintf(v.x / scale), -128.f), 127.f) * scale;
    o.y = fminf(fmaxf(rintf(v.y / scale), -128.f), 127.f) * scale;
    o.z = fminf(fmaxf(rintf(v.z / scale), -128.f), 127.f) * scale;
    o.w = fminf(fmaxf(rintf(v.w / scale), -128.f), 127.f) * scale;
    ((float4*)d.out)[i] = o;
  }
}

// generic fake-quant -> i8 (same layout)
__global__ __launch_bounds__(256) void quant8_kernel(const float* __restrict__ in,
                                                     signed char* __restrict__ out8, long n4,
                                                     const float* __restrict__ amax_p,
                                                     float pre, float qmin) {
  float scale = fmaxf(amax_p[0] * pre / 127.f, 1e-8f);
  long stride = (long)gridDim.x * 256;
  for (long i = (long)blockIdx.x * 256 + threadIdx.x; i < n4; i += stride) {
    float4 v = ((const float4*)in)[i];
    char4 o;
    o.x = (signed char)(int)fminf(fmaxf(rintf(v.x * pre / scale), qmin), 127.f);
    o.y = (signed char)(int)fminf(fmaxf(rintf(v.y * pre / scale), qmin), 127.f);
    o.z = (signed char)(int)fminf(fmaxf(rintf(v.z * pre / scale), qmin), 127.f);
    o.w = (signed char)(int)fminf(fmaxf(rintf(v.w * pre / scale), qmin), 127.f);
    ((char4*)out8)[i] = o;
  }
}

// relu + unsigned 8-bit quant -> codes stored as (c - 128) in signed i8
__global__ __launch_bounds__(256) void relu_quant8_kernel(const float* __restrict__ in,
                                                          signed char* __restrict__ out8, long n4,
                                                          const float* __restrict__ amax_p) {
  float scale = fmaxf(amax_p[0] / 255.f, 1e-8f);
  long stride = (long)gridDim.x * 256;
  for (long i = (long)blockIdx.x * 256 + threadIdx.x; i < n4; i += stride) {
    float4 v = ((const float4*)in)[i];
    char4 o;
    o.x = (signed char)((int)fminf(fmaxf(rintf(fmaxf(v.x, 0.f) / scale), 0.f), 255.f) - 128);
    o.y = (signed char)((int)fminf(fmaxf(rintf(fmaxf(v.y, 0.f) / scale), 0.f), 255.f) - 128);
    o.z = (signed char)((int)fminf(fmaxf(rintf(fmaxf(v.z, 0.f) / scale), 0.f), 255.f) - 128);
    o.w = (signed char)((int)fminf(fmaxf(rintf(fmaxf(v.w, 0.f) / scale), 0.f), 255.f) - 128);
    ((char4*)out8)[i] = o;
  }
}

// per-row sum of int8 codes (for unsigned-offset correction); one block per row
__global__ __launch_bounds__(256) void rowsum_i8_kernel(const signed char* __restrict__ w8,
                                                        int* __restrict__ out, int Kdim) {
  const int row = blockIdx.x, t = threadIdx.x;
  const signed char* p = w8 + (long)row * Kdim;
  int s = 0;
  for (int i = t * 16; i < Kdim; i += 4096) {
    int4v v = *(const int4v*)(p + i);
    const signed char* b = (const signed char*)&v;
#pragma unroll
    for (int j = 0; j < 16; j++) s += b[j];
  }
#pragma unroll
  for (int o = 32; o; o >>= 1) s += __shfl_down(s, o, 64);
  __shared__ int sm[4];
  if (!(t & 63)) sm[t >> 6] = s;
  __syncthreads();
  if (t == 0) out[row] = sm[0] + sm[1] + sm[2] + sm[3];
}

// ---------------------------------------------------------------------------
// int8 MFMA NT GEMM (exact): C[M,N] = (sum_k A8[m,k]*B8[n,k] + corr) * s_a*s_b + bias[n]
//
// R7 post-mortem: 64x64 tiles gave occupancy but halved arithmetic intensity
// -> FETCH 24.7->67.9MB, dur worse. R2-R6: at 1 block/CU no intra-block
// schedule moves the time (confirmed externally: m102's verified kernel drops
// 874->~90TF-equivalent exactly at 1 block/CU grids).
//
// This version: RECTANGULAR 64(M) x 128(N) tile, 256 threads, 4 waves, each
// wave keeping R5's proven 32x64 geometry (acc[2][4] = 32 regs, spill-free).
// N=1024 GEMMs -> 8x64 = 512 blocks = 2 INDEPENDENT blocks/CU (first real
// TLP for Wo/MLP2); QKV 1536, MLP1 2048 blocks. L2 math: traffic = A x8 +
// B x64 = 384MB (vs R7's 512), per-XCD set = B 4MB + A-band 2MB = same ratio
// as the proven 128^2 config -> FETCH should stay ~compulsory.
// LDS: (A 4KB + B 8KB) x 2 buffers = 24KB -> 2+ blocks/CU. R5's 2-buffer
// counted-vmcnt loop (3 loads/tile -> vmcnt(3)). XOR slot swizzle unchanged
// (B's second half rows r0+64: (r0+64)>>1 shifts XOR index by 32 == 0 mod 4).
// ---------------------------------------------------------------------------
__global__ __launch_bounds__(256, 4) void gemm_i8_kernel(
    const signed char* __restrict__ A, const signed char* __restrict__ Bw,
    const float* __restrict__ biasq,
    const float* __restrict__ amax_a, float div_a,
    const float* __restrict__ amax_b,
    const int* __restrict__ rowsum,           // nullable: adds 128*rowsum[n]
    float* __restrict__ C, int M, int N, int K,
    float* __restrict__ amax_out, int relu_amax, int mode) {
  __shared__ signed char Asm[2][4096];  // 64 rows x 64B, K-contiguous
  __shared__ signed char Bsm[2][8192];  // 128 rows x 64B
  __shared__ float redm[4];
  const int t = threadIdx.x;
  // XCD-aware swizzle (gridDim.y % 8 == 0): xcd gets M-band [xcd*gy/8 .. )
  int bx, by;
  {
    int lin = blockIdx.y * gridDim.x + blockIdx.x;
    if ((gridDim.y & 7) == 0) {
      int xcd = lin & 7, j = lin >> 3;
      bx = j % gridDim.x;
      by = (gridDim.y >> 3) * xcd + j / gridDim.x;
    } else { bx = blockIdx.x; by = blockIdx.y; }
  }
  const int m0 = by * 64, n0 = bx * 128;
  const int w = t >> 6, lane = t & 63;
  const int fr = lane & 15, quad = lane >> 4;
  const int wm = w >> 1, wn = w & 1;    // 2x2: wave owns rows wm*32, cols wn*64
  const int r0 = t >> 2;                // staging row 0..63 (256 threads)
  // Swizzle: LDS(row r, slot s) holds global(row r, slot s ^ ((r>>1)&3)).
  const int csrc = (((t & 3) ^ ((t >> 3) & 3)) << 4);
  // Read side: LDS slot = quad ^ ((fr>>1)&3) (same involution).
  const int sx = ((quad ^ ((fr >> 1) & 3)) << 4);

  int4v acc[2][4];
#pragma unroll
  for (int r = 0; r < 2; r++)
#pragma unroll
    for (int c = 0; c < 4; c++) acc[r][c] = (int4v){0, 0, 0, 0};

  const long arow  = (long)(m0 + r0) * K + csrc;
  const long brow0 = (long)(n0 + r0) * K + csrc;
  const long brow1 = (long)(n0 + r0 + 64) * K + csrc;

  auto stage = [&](int buf, int kt) {
    const int kk = kt << 6;
    gl2lds16(A + arow + kk, Asm[buf] + t * 16);
    gl2lds16(Bw + brow0 + kk, Bsm[buf] + t * 16);
    gl2lds16(Bw + brow1 + kk, Bsm[buf] + t * 16 + 4096);
  };
  auto compute = [&](int buf) {
    int4v af[2], bf[4];
#pragma unroll
    for (int r = 0; r < 2; r++)
      af[r] = *(const int4v*)(Asm[buf] + (wm * 32 + r * 16 + fr) * 64 + sx);
#pragma unroll
    for (int c = 0; c < 4; c++)
      bf[c] = *(const int4v*)(Bsm[buf] + (wn * 64 + c * 16 + fr) * 64 + sx);
#pragma unroll
    for (int r = 0; r < 2; r++)
#pragma unroll
      for (int c = 0; c < 4; c++)
        acc[r][c] = __builtin_amdgcn_mfma_i32_16x16x64_i8(af[r], bf[c], acc[r][c], 0, 0, 0);
  };

  const int nt = K >> 6;  // 16 (K=1024) or 64 (K=4096)
  stage(0, 0);
  int buf = 0;
  for (int kt = 0; kt < nt; ++kt) {
    if (kt + 1 < nt) {
      stage(buf ^ 1, kt + 1);  // buf^1's previous readers all passed last barrier
      __asm__ volatile("s_waitcnt vmcnt(3)" ::: "memory");  // tile kt resident (this wave)
    } else {
      __asm__ volatile("s_waitcnt vmcnt(0)" ::: "memory");
    }
    RAW_BARRIER();             // -> tile kt resident for ALL waves
    compute(buf);
    RAW_BARRIER();             // all waves' ds_reads of buf done -> re-stageable
    buf ^= 1;
  }

  // --- epilogue ---
  const int seg = (mode == 1) ? (n0 >> 10) : 0;
  const float s_a = fmaxf(amax_a[0] / div_a, 1e-8f);
  const float s_b = fmaxf(amax_b[seg] / 127.f, 1e-8f);
  const float s = s_a * s_b;
  float lmax = 0.f;
#pragma unroll
  for (int r = 0; r < 2; r++) {
    int rbase = m0 + wm * 32 + r * 16 + quad * 4;
#pragma unroll
    for (int c = 0; c < 4; c++) {
      int col = n0 + wn * 64 + c * 16 + fr;
      int corr = rowsum ? (rowsum[col] << 7) : 0;
      float bi = biasq[col];
      if (mode == 1) {
        // segment-local fp32 [B,H,S,D] write
        int h = (col >> 6) & 15, dd = col & 63;
        float* cbase = C + (long)seg * ((long)TB_ROWS * TB_E);
#pragma unroll
        for (int g = 0; g < 4; g++) {
          int m = rbase + g;
          int b = m >> 10, sdx = m & 1023;
          float o = (float)acc[r][c][g] * s + bi;
          lmax = fmaxf(lmax, fabsf(o));
          cbase[((((long)b * TB_H + h) * TB_S) + sdx) * TB_D + dd] = o;
        }
      } else {
#pragma unroll
        for (int g = 0; g < 4; g++) {
          float o = (float)(acc[r][c][g] + corr) * s + bi;
          lmax = fmaxf(lmax, relu_amax ? fmaxf(o, 0.f) : fabsf(o));
          C[(long)(rbase + g) * N + col] = o;
        }
      }
    }
  }
#pragma unroll
  for (int o = 32; o; o >>= 1) lmax = fmaxf(lmax, __shfl_down(lmax, o, 64));
  if (!lane) redm[w] = lmax;
  __syncthreads();
  if (t == 0)
    atomicMaxF(amax_out + seg, fmaxf(fmaxf(redm[0], redm[1]), fmaxf(redm[2], redm[3])));
}

// ---------------------------------------------------------------------------
// v quant + transpose: fp32 [B,H,S,D] -> i8 blocked [BH][jb][D][64]
// ---------------------------------------------------------------------------
__global__ __launch_bounds__(256) void quant8_vb_kernel(const float* __restrict__ v,
                                                        const float* __restrict__ amax_p,
                                                        signed char* __restrict__ v8b) {
  __shared__ signed char tile[64][80];  // [d][s], stride 80
  const int bh = blockIdx.x;
  const int jb = blockIdx.y;
  const int s0 = jb * 64;
  const int t = threadIdx.x;
  const float scale = fmaxf(amax_p[0] / 127.f, 1e-8f);
#pragma unroll
  for (int it = 0; it < 4; it++) {
    int idx = t + it * 256;           // 0..1023 float4 slots
    int r = idx >> 4, c4 = (idx & 15) * 4;
    float4 vv = *(const float4*)(v + ((long)bh * TB_S + s0 + r) * TB_D + c4);
    tile[c4 + 0][r] = (signed char)(int)fminf(fmaxf(rintf(vv.x / scale), -128.f), 127.f);
    tile[c4 + 1][r] = (signed char)(int)fminf(fmaxf(rintf(vv.y / scale), -128.f), 127.f);
    tile[c4 + 2][r] = (signed char)(int)fminf(fmaxf(rintf(vv.z / scale), -128.f), 127.f);
    tile[c4 + 3][r] = (signed char)(int)fminf(fmaxf(rintf(vv.w / scale), -128.f), 127.f);
  }
  __syncthreads();
  int d = t >> 2, sb = (t & 3) * 16;
  int4v o = *(const int4v*)&tile[d][sb];
  *(int4v*)(v8b + (((long)bh * 16 + jb) * 64 + d) * 64 + sb) = o;
}

// ---------------------------------------------------------------------------
// Attention pass A: per-row signed int max of scores -> irowmax; global int
// absmax -> imax_out. q8/k8 in [B,H,S,D]; wave loads are 1KB contiguous.
// D[m=j][n=i]: lane (fr,quad) holds i = i0+fr, j = j0 + quad*4 + g.
// ---------------------------------------------------------------------------
__global__ __launch_bounds__(256) void attn_rowmax_kernel(const signed char* __restrict__ q8,
                                                          const signed char* __restrict__ k8,
                                                          int* __restrict__ irowmax,
                                                          int* __restrict__ imax_out) {
  const int bh = blockIdx.x;
  const int t = threadIdx.x, w = t >> 6, lane = t & 63;
  const int fr = lane & 15, quad = lane >> 4;
  const int i0 = blockIdx.y * 64 + w * 16;
  const long base = (long)bh * TB_S;
  int4v qf = *(const int4v*)(q8 + (base + i0 + fr) * 64 + quad * 16);
  int mx = -2147483647, mn = 2147483647;
  for (int j0 = 0; j0 < TB_S; j0 += 16) {
    int4v kf = *(const int4v*)(k8 + (base + j0 + fr) * 64 + quad * 16);
    int4v sc = __builtin_amdgcn_mfma_i32_16x16x64_i8(kf, qf, (int4v){0, 0, 0, 0}, 0, 0, 0);
    mx = max(mx, max(max(sc[0], sc[1]), max(sc[2], sc[3])));
    mn = min(mn, min(min(sc[0], sc[1]), min(sc[2], sc[3])));
  }
  mx = max(mx, __shfl_xor(mx, 16, 64));
  mx = max(mx, __shfl_xor(mx, 32, 64));
  mn = min(mn, __shfl_xor(mn, 16, 64));
  mn = min(mn, __shfl_xor(mn, 32, 64));
  if (quad == 0) irowmax[(long)bh * TB_S + i0 + fr] = mx;
  int gm = max(mx, -mn);
#pragma unroll
  for (int o = 32; o; o >>= 1) gm = max(gm, __shfl_down(gm, o, 64));
  __shared__ int sm[4];
  if (!lane) sm[w] = gm;
  __syncthreads();
  if (t == 0) atomicMax(imax_out, max(max(sm[0], sm[1]), max(sm[2], sm[3])));
}

// ---------------------------------------------------------------------------
// Attention pass B: l = sum exp2((qv - qmax)*aa) per row. rowl <- l;
// amax_attn <- max(1/l). NOTE: the qv clamps to [-128,127] are mathematically
// dead (|sc| <= imax -> |sc*c1| <= 127) and are dropped; pass C's clamped
// form computes identical values, so codes stay consistent.
// ---------------------------------------------------------------------------
__global__ __launch_bounds__(256) void attn_rowsum_kernel(
    const signed char* __restrict__ q8, const signed char* __restrict__ k8,
    const int* __restrict__ irowmax, const int* __restrict__ imax_p,
    const float* __restrict__ amax_q, const float* __restrict__ amax_k,
    float* __restrict__ rowl, float* __restrict__ amax_attn) {
  const int bh = blockIdx.x;
  const int t = threadIdx.x, w = t >> 6, lane = t & 63;
  const int fr = lane & 15, quad = lane >> 4;
  const int i0 = blockIdx.y * 64 + w * 16;
  const float s_q = fmaxf(amax_q[0] * 0.125f / 127.f, 1e-8f);
  const float s_k = fmaxf(amax_k[0] / 127.f, 1e-8f);
  const float sqk = s_q * s_k;
  const float s_sc = fmaxf((float)imax_p[0] * sqk / 127.f, 1e-8f);
  const float c1 = sqk / s_sc;
  const float aa = s_sc * 1.44269504088896340736f;
  const long base = (long)bh * TB_S;
  int4v qf = *(const int4v*)(q8 + (base + i0 + fr) * 64 + quad * 16);
  const int imr = irowmax[base + i0 + fr];
  const float qmax = fminf(fmaxf(rintf((float)imr * c1), -128.f), 127.f);
  const float qa = qmax * aa;
  float l = 0.f;
  for (int j0 = 0; j0 < TB_S; j0 += 16) {
    int4v kf = *(const int4v*)(k8 + (base + j0 + fr) * 64 + quad * 16);
    int4v sc = __builtin_amdgcn_mfma_i32_16x16x64_i8(kf, qf, (int4v){0, 0, 0, 0}, 0, 0, 0);
#pragma unroll
    for (int g = 0; g < 4; g++) {
      float qv = rintf((float)sc[g] * c1);   // clamps dead: |sc*c1| <= 127
      l += fast_exp2(fmaf(qv, aa, -qa));
    }
  }
  l += __shfl_xor(l, 16, 64);
  l += __shfl_xor(l, 32, 64);
  if (quad == 0) rowl[base + i0 + fr] = l;
  float inv = 1.f / l;                        // row max of softmax = 1/l
#pragma unroll
  for (int o = 32; o; o >>= 1) inv = fmaxf(inv, __shfl_down(inv, o, 64));
  __shared__ float smf[4];
  if (!lane) smf[w] = inv;
  __syncthreads();
  if (t == 0) atomicMaxF(amax_attn, fmaxf(fmaxf(smf[0], smf[1]), fmaxf(smf[2], smf[3])));
}

// ---------------------------------------------------------------------------
// Attention pass C: recompute scores (identical expr -> identical codes),
// attn code = rint(exp2(qv*aa - bexp) * invls); per-wave LDS transpose (no
// block barriers); PV MFMA on blocked v8b. ctx fp32 [B,S,H,D] + fused absmax.
// (R5-measured 46.1us version restored: R6 magic-round and R7 pipelining were
// neutral-to-negative.)
// ---------------------------------------------------------------------------
__global__ __launch_bounds__(256) void attn_pv_kernel(
    const signed char* __restrict__ q8, const signed char* __restrict__ k8,
    const signed char* __restrict__ v8b,
    const int* __restrict__ irowmax, const int* __restrict__ imax_p,
    const float* __restrict__ amax_q, const float* __restrict__ amax_k,
    const float* __restrict__ amax_v, const float* __restrict__ amax_attn,
    const float* __restrict__ rowl,
    float* __restrict__ ctx, float* __restrict__ amax_ctx) {
  __shared__ signed char latt[4][16][80];  // [wave][i-rel][j-byte], stride 80
  const int bh = blockIdx.x, b = bh >> 4, h = bh & 15;
  const int t = threadIdx.x, w = t >> 6, lane = t & 63;
  const int fr = lane & 15, quad = lane >> 4;
  const int i0 = blockIdx.y * 64 + w * 16;
  const float s_q = fmaxf(amax_q[0] * 0.125f / 127.f, 1e-8f);
  const float s_k = fmaxf(amax_k[0] / 127.f, 1e-8f);
  const float sqk = s_q * s_k;
  const float s_sc = fmaxf((float)imax_p[0] * sqk / 127.f, 1e-8f);
  const float c1 = sqk / s_sc;
  const float aa = s_sc * 1.44269504088896340736f;
  const float s_v = fmaxf(amax_v[0] / 127.f, 1e-8f);
  const float s_at = fmaxf(amax_attn[0] / 127.f, 1e-8f);
  const long base = (long)bh * TB_S;
  int4v qf = *(const int4v*)(q8 + (base + i0 + fr) * 64 + quad * 16);
  const int imr = irowmax[base + i0 + fr];
  const float qmax = fminf(fmaxf(rintf((float)imr * c1), -128.f), 127.f);
  const float bexp = qmax * aa;
  const float li = rowl[base + i0 + fr];
  const float invls = 1.f / (li * s_at);             // one exact div per row
  int4v accv[4];
#pragma unroll
  for (int dtile = 0; dtile < 4; dtile++) accv[dtile] = (int4v){0, 0, 0, 0};

  for (int j0 = 0; j0 < TB_S; j0 += 64) {
#pragma unroll
    for (int tt = 0; tt < 4; tt++) {
      int4v kf = *(const int4v*)(k8 + (base + j0 + tt * 16 + fr) * 64 + quad * 16);
      int4v sc = __builtin_amdgcn_mfma_i32_16x16x64_i8(kf, qf, (int4v){0, 0, 0, 0}, 0, 0, 0);
      int packed = 0;
#pragma unroll
      for (int g = 0; g < 4; g++) {
        float qv = fminf(fmaxf(rintf((float)sc[g] * c1), -128.f), 127.f);
        float e = fast_exp2(fmaf(qv, aa, -bexp));
        int code = (int)fminf(fmaxf(rintf(e * invls), -128.f), 127.f);
        packed |= (code & 255) << (g * 8);
      }
      *(int*)&latt[w][fr][tt * 16 + quad * 4] = packed;
    }
    LGKM0();   // wave-private LDS: ds in-order per wave, no block barrier needed
    int4v af = *(const int4v*)&latt[w][fr][quad * 16];
    const signed char* vbase = v8b + (((long)bh * 16 + (j0 >> 6)) * 64) * 64;
#pragma unroll
    for (int dtile = 0; dtile < 4; dtile++) {
      int4v vf = *(const int4v*)(vbase + (dtile * 16 + fr) * 64 + quad * 16);
      accv[dtile] = __builtin_amdgcn_mfma_i32_16x16x64_i8(af, vf, accv[dtile], 0, 0, 0);
    }
    CMEMBAR(); // keep next iteration's ds_writes after this read (in-order DS)
  }
  const float sav = s_at * s_v;
  float cmax = 0.f;
#pragma unroll
  for (int dtile = 0; dtile < 4; dtile++) {
#pragma unroll
    for (int g = 0; g < 4; g++) {
      float val = (float)accv[dtile][g] * sav;
      cmax = fmaxf(cmax, fabsf(val));
      int irow = i0 + quad * 4 + g;
      ctx[(((long)(b * TB_S + irow)) * TB_H + h) * TB_D + dtile * 16 + fr] = val;
    }
  }
#pragma unroll
  for (int o = 32; o; o >>= 1) cmax = fmaxf(cmax, __shfl_down(cmax, o, 64));
  __shared__ float smf[4];
  if (!lane) smf[w] = cmax;
  __syncthreads();
  if (t == 0) atomicMaxF(amax_ctx, fmaxf(fmaxf(smf[0], smf[1]), fmaxf(smf[2], smf[3])));
}

// ---------------------------------------------------------------------------
// h = LayerNorm(dequant(a8) + fakequant(braw)); fused output absmax.
// Wave-per-row (4 rows/block), single-pass sum+sumsq (var = E[x^2]-mu^2),
// no block barriers in the main path.
// ---------------------------------------------------------------------------
__global__ __launch_bounds__(256) void resid_ln_kernel(const signed char* __restrict__ a8,
                                                       const float* __restrict__ amax_a,
                                                       const float* __restrict__ braw,
                                                       const float* __restrict__ amax_b,
                                                       float* __restrict__ outp,
                                                       float* __restrict__ amax_out) {
  const int t = threadIdx.x, w = t >> 6, lane = t & 63;
  const int row = blockIdx.x * 4 + w;
  const float sa = fmaxf(amax_a[0] / 127.f, 1e-8f);
  const float sb = fmaxf(amax_b[0] / 127.f, 1e-8f);
  const long base = (long)row * TB_E;
  float v[16];
  float s = 0.f, q = 0.f;
#pragma unroll
  for (int j = 0; j < 4; j++) {
    char4 a = ((const char4*)(a8 + base))[j * 64 + lane];
    float4 bv = *(const float4*)(braw + base + j * 256 + lane * 4);
    float x0 = (float)a.x * sa + fminf(fmaxf(rintf(bv.x / sb), -128.f), 127.f) * sb;
    float x1 = (float)a.y * sa + fminf(fmaxf(rintf(bv.y / sb), -128.f), 127.f) * sb;
    float x2 = (float)a.z * sa + fminf(fmaxf(rintf(bv.z / sb), -128.f), 127.f) * sb;
    float x3 = (float)a.w * sa + fminf(fmaxf(rintf(bv.w / sb), -128.f), 127.f) * sb;
    v[j * 4 + 0] = x0; v[j * 4 + 1] = x1; v[j * 4 + 2] = x2; v[j * 4 + 3] = x3;
    s += (x0 + x1) + (x2 + x3);
    q += (x0 * x0 + x1 * x1) + (x2 * x2 + x3 * x3);
  }
  // dual wave-allreduce (independent chains -> ILP overlap)
#pragma unroll
  for (int o = 32; o; o >>= 1) {
    s += __shfl_xor(s, o, 64);
    q += __shfl_xor(q, o, 64);
  }
  const float mu = s * (1.f / TB_E);
  const float var = fmaxf(q * (1.f / TB_E) - mu * mu, 0.f);
  const float rs = 1.f / sqrtf(var + 1e-5f);
  float lm = 0.f;
#pragma unroll
  for (int j = 0; j < 4; j++) {
    float4 o4;
    o4.x = (v[j * 4 + 0] - mu) * rs;
    o4.y = (v[j * 4 + 1] - mu) * rs;
    o4.z = (v[j * 4 + 2] - mu) * rs;
    o4.w = (v[j * 4 + 3] - mu) * rs;
    *(float4*)(outp + base + j * 256 + lane * 4) = o4;
    lm = fmaxf(lm, fmaxf(fmaxf(fabsf(o4.x), fabsf(o4.y)), fmaxf(fabsf(o4.z), fabsf(o4.w))));
  }
#pragma unroll
  for (int o = 32; o; o >>= 1) lm = fmaxf(lm, __shfl_down(lm, o, 64));
  __shared__ float redm[4];
  if (!lane) redm[w] = lm;
  __syncthreads();
  if (t == 0) atomicMaxF(amax_out, fmaxf(fmaxf(redm[0], redm[1]), fmaxf(redm[2], redm[3])));
}

// ---------------------------------------------------------------------------
// Host side
// ---------------------------------------------------------------------------
#define SL_X 0
#define SL_WQ 1
#define SL_WK 2
#define SL_WV 3
#define SL_WO 4
#define SL_W1 5
#define SL_W2 6
#define SL_BQ 7
#define SL_BK 8
#define SL_BV 9
#define SL_BO 10
#define SL_B1 11
#define SL_B2 12
#define SL_Q 13   // SL_K = 14, SL_V = 15 must stay consecutive (QKV epilogue)
#define SL_K 14
#define SL_V 15
#define SL_SCI 16     // int imax of scores
#define SL_ATTN 17
#define SL_CTX 18
#define SL_AO 19
#define SL_H 20
#define SL_RELU 21
#define SL_M2 22
#define SL_DUMMY 23

static inline int nblocks(long n) {
  long b = (n + 255) / 256;
  return (int)(b > 2048 ? 2048 : b);
}

extern "C" void kernel_launch(void* const* d_in, const int* in_sizes, int n_in,
                              void* d_out, int out_size, void* d_ws, size_t ws_size,
                              hipStream_t stream) {
  const float* x  = (const float*)d_in[0];
  const float* Wq = (const float*)d_in[1];
  const float* bq = (const float*)d_in[2];
  const float* Wk = (const float*)d_in[3];
  const float* bk = (const float*)d_in[4];
  const float* Wv = (const float*)d_in[5];
  const float* bv = (const float*)d_in[6];
  const float* Wo = (const float*)d_in[7];
  const float* bo = (const float*)d_in[8];
  const float* W1 = (const float*)d_in[9];
  const float* b1 = (const float*)d_in[10];
  const float* W2 = (const float*)d_in[11];
  const float* b2 = (const float*)d_in[12];
  float* ws = (float*)d_ws;
  float* out = (float*)d_out;

  const long SZ_XE = (long)TB_ROWS * TB_E;      // 4,194,304
  const long SZ_W  = (long)TB_E * TB_E;         // 1,048,576
  const long SZ_M1 = (long)TB_ROWS * TB_MLP;    // 16,777,216

  // float-offset layout
  const long OFF_QBQ = 1024, OFF_QBK = 2048, OFF_QBV = 3072, OFF_QBO = 4096;
  const long OFF_QB1 = 5120, OFF_QB2 = 9216;
  const long OFF_RSUM = 10240;                  // int32[1024]
  const long OFF_Q  = 65536;                    // fp32 q [B,H,S,D], later ctx
  const long OFF_K  = OFF_Q + SZ_XE;            // fp32 k [B,H,S,D], later attn_out
  const long OFF_V  = OFF_K + SZ_XE;            // fp32 v [B,H,S,D], later h
  const long OFF_M2 = OFF_V + SZ_XE;            // fp32 m2
  const long OFF_IRM = OFF_M2 + SZ_XE;          // int irowmax [65536]
  const long OFF_ROWL = OFF_IRM + 65536;
  const long OFF_M1 = OFF_ROWL + 65536;         // fp32 m1 (64MB)
  const long OFF_I8 = OFF_M1 + SZ_M1;           // i8 region start (float offset)

  float* qbuf = ws + OFF_Q;  float* kbuf = ws + OFF_K;  float* vbuf = ws + OFF_V;
  float* m2   = ws + OFF_M2;
  int*   irowmax = (int*)(ws + OFF_IRM);
  float* rowl = ws + OFF_ROWL;
  float* m1 = ws + OFF_M1;
  float* ctx = qbuf;        // reuse q (q8 codes already extracted)
  float* attn_out = kbuf;   // reuse k
  float* hbuf = vbuf;       // reuse v
  float* qbq_ = ws + OFF_QBQ; float* qbk_ = ws + OFF_QBK;
  float* qbv_ = ws + OFF_QBV; float* qbo_ = ws + OFF_QBO;
  float* qb1_ = ws + OFF_QB1; float* qb2_ = ws + OFF_QB2;
  int* rsum = (int*)(ws + OFF_RSUM);
  int* imax = (int*)(ws + SL_SCI);

  // i8 code buffers (byte pointers)
  signed char* i8base = (signed char*)(ws + OFF_I8);
  signed char* qx8  = i8base;                   // 4096x1024 [rows,E]
  signed char* wq8  = qx8 + SZ_XE;              // 1024x1024  (wq8,wk8,wv8 contiguous for QKV fusion)
  signed char* wk8  = wq8 + SZ_W;
  signed char* wv8  = wk8 + SZ_W;
  signed char* wo8  = wv8 + SZ_W;
  signed char* w18  = wo8 + SZ_W;               // 4096x1024
  signed char* w28  = w18 + SZ_XE;              // 1024x4096
  signed char* ctx8 = w28 + SZ_XE;              // 4096x1024
  signed char* m08  = ctx8 + SZ_XE;             // 4096x1024
  signed char* m18  = m08 + SZ_XE;              // 4096x4096 (relu codes - 128)
  signed char* q8   = m18 + SZ_M1;              // [B,H,S,D]
  signed char* k8   = q8 + SZ_XE;               // [B,H,S,D]
  signed char* v8b  = k8 + SZ_XE;               // [BH][16][64][64]

  hipMemsetAsync(ws, 0, 4096, stream);  // zero scalar slots

  // --- absmax of all 13 inputs (1 dispatch) ---
  AMBatch am;
  am.d[0]  = {x,  SZ_XE/4, SL_X};
  am.d[1]  = {Wq, SZ_W/4,  SL_WQ};
  am.d[2]  = {Wk, SZ_W/4,  SL_WK};
  am.d[3]  = {Wv, SZ_W/4,  SL_WV};
  am.d[4]  = {Wo, SZ_W/4,  SL_WO};
  am.d[5]  = {W1, SZ_XE/4, SL_W1};
  am.d[6]  = {W2, SZ_XE/4, SL_W2};
  am.d[7]  = {bq, 256,     SL_BQ};
  am.d[8]  = {bk, 256,     SL_BK};
  am.d[9]  = {bv, 256,     SL_BV};
  am.d[10] = {bo, 256,     SL_BO};
  am.d[11] = {b1, 1024,    SL_B1};
  am.d[12] = {b2, 256,     SL_B2};
  absmax_multi_kernel<<<dim3(64, 13), 256, 0, stream>>>(am, ws);

  // --- quantize x + 6 weights to i8 codes (1 dispatch); biases (1 dispatch) ---
  QMBatch qm;
  qm.d[0] = {x,  qx8, SZ_XE/4, SL_X,  -128.f};
  qm.d[1] = {Wq, wq8, SZ_W/4,  SL_WQ, -127.f};
  qm.d[2] = {Wk, wk8, SZ_W/4,  SL_WK, -127.f};
  qm.d[3] = {Wv, wv8, SZ_W/4,  SL_WV, -127.f};
  qm.d[4] = {W1, w18, SZ_XE/4, SL_W1, -127.f};
  qm.d[5] = {W2, w28, SZ_XE/4, SL_W2, -127.f};
  qm.d[6] = {Wo, wo8, SZ_W/4,  SL_WO, -127.f};
  quant8_multi_kernel<<<dim3(64, 7), 256, 0, stream>>>(qm, ws);
  rowsum_i8_kernel<<<TB_E, 256, 0, stream>>>(w28, rsum, TB_MLP);
  BBatch bb;
  bb.d[0] = {bq, qbq_, 256,  SL_BQ};
  bb.d[1] = {bk, qbk_, 256,  SL_BK};
  bb.d[2] = {bv, qbv_, 256,  SL_BV};
  bb.d[3] = {bo, qbo_, 256,  SL_BO};
  bb.d[4] = {b1, qb1_, 1024, SL_B1};
  bb.d[5] = {b2, qb2_, 256,  SL_B2};
  bias_quant_multi_kernel<<<dim3(4, 6), 256, 0, stream>>>(bb, ws);

  // --- fused QKV in-projection (int8 MFMA, exact): N=3072, writes [B,H,S,D] fp32 ---
  gemm_i8_kernel<<<dim3(3*TB_E/128, TB_ROWS/64), 256, 0, stream>>>(
      qx8, wq8, qbq_, ws + SL_X, 127.f, ws + SL_WQ, nullptr, qbuf,
      TB_ROWS, 3*TB_E, TB_E, ws + SL_Q, 0, 1);

  // --- quantize q (pre=1/8), k (linear, layouts already [B,H,S,D]); v blocked ---
  quant8_kernel<<<2048, 256, 0, stream>>>(qbuf, q8, SZ_XE/4, ws + SL_Q, 0.125f, -128.f);
  quant8_kernel<<<2048, 256, 0, stream>>>(kbuf, k8, SZ_XE/4, ws + SL_K, 1.f, -128.f);
  quant8_vb_kernel<<<dim3(TB_B*TB_H, TB_S/64), 256, 0, stream>>>(vbuf, ws + SL_V, v8b);

  // --- attention (i8 MFMA, 3 passes) ---
  attn_rowmax_kernel<<<dim3(TB_B*TB_H, TB_S/64), 256, 0, stream>>>(q8, k8, irowmax, imax);
  attn_rowsum_kernel<<<dim3(TB_B*TB_H, TB_S/64), 256, 0, stream>>>(
      q8, k8, irowmax, imax, ws + SL_Q, ws + SL_K, rowl, ws + SL_ATTN);
  attn_pv_kernel<<<dim3(TB_B*TB_H, TB_S/64), 256, 0, stream>>>(
      q8, k8, v8b, irowmax, imax, ws + SL_Q, ws + SL_K, ws + SL_V, ws + SL_ATTN,
      rowl, ctx, ws + SL_CTX);

  // --- out projection ---
  quant8_kernel<<<2048, 256, 0, stream>>>(ctx, ctx8, SZ_XE/4, ws + SL_CTX, 1.f, -128.f);
  gemm_i8_kernel<<<dim3(TB_E/128, TB_ROWS/64), 256, 0, stream>>>(
      ctx8, wo8, qbo_, ws + SL_CTX, 127.f, ws + SL_WO, nullptr, attn_out,
      TB_ROWS, TB_E, TB_E, ws + SL_AO, 0, 0);

  // --- residual + LN (fused h absmax) ---
  resid_ln_kernel<<<TB_ROWS/4, 256, 0, stream>>>(qx8, ws + SL_X, attn_out, ws + SL_AO, hbuf, ws + SL_H);

  // --- MLP ---
  quant8_kernel<<<2048, 256, 0, stream>>>(hbuf, m08, SZ_XE/4, ws + SL_H, 1.f, -128.f);
  gemm_i8_kernel<<<dim3(TB_MLP/128, TB_ROWS/64), 256, 0, stream>>>(
      m08, w18, qb1_, ws + SL_H, 127.f, ws + SL_W1, nullptr, m1,
      TB_ROWS, TB_MLP, TB_E, ws + SL_RELU, 1, 0);
  relu_quant8_kernel<<<nblocks(SZ_M1/4), 256, 0, stream>>>(m1, m18, SZ_M1/4, ws + SL_RELU);
  gemm_i8_kernel<<<dim3(TB_E/128, TB_ROWS/64), 256, 0, stream>>>(
      m18, w28, qb2_, ws + SL_RELU, 255.f, ws + SL_W2, rsum, m2,
      TB_ROWS, TB_E, TB_MLP, ws + SL_M2, 0, 0);

  // --- final residual + LN ---
  resid_ln_kernel<<<TB_ROWS/4, 256, 0, stream>>>(m08, ws + SL_H, m2, ws + SL_M2, out, ws + SL_DUMMY);
}

// Round 9
// 454.921 us; speedup vs baseline: 1.1556x; 1.0681x over previous
//
#include <hip/hip_runtime.h>
#include <cstdint>
#include <cstddef>

// Problem constants
#define TB_B 4
#define TB_S 1024
#define TB_E 1024
#define TB_H 16
#define TB_D 64
#define TB_MLP 4096
#define TB_ROWS (TB_B * TB_S)   // 4096

typedef int int4v __attribute__((ext_vector_type(4)));

#define LGKM0() __asm__ volatile("s_waitcnt lgkmcnt(0)" ::: "memory")
#define CMEMBAR() __asm__ volatile("" ::: "memory")
// raw barrier with compiler memory fences (no vmcnt drain, unlike __syncthreads)
#define RAW_BARRIER() do { __asm__ volatile("" ::: "memory"); \
  __builtin_amdgcn_s_barrier(); __asm__ volatile("" ::: "memory"); } while (0)

static __device__ __forceinline__ void atomicMaxF(float* addr, float v) {
  // valid for non-negative floats: IEEE bit pattern is monotonic
  atomicMax(reinterpret_cast<unsigned int*>(addr), __float_as_uint(v));
}

static __device__ __forceinline__ float fast_exp2(float x) {
#if __has_builtin(__builtin_amdgcn_exp2f)
  return __builtin_amdgcn_exp2f(x);
#else
  return exp2f(x);
#endif
}

// async global->LDS, 16 bytes per lane. LDS dest must be wave-uniform base + lane*16.
static __device__ __forceinline__ void gl2lds16(const void* g, void* l) {
  __builtin_amdgcn_global_load_lds(
      (const __attribute__((address_space(1))) void*)g,
      (__attribute__((address_space(3))) void*)l, 16, 0, 0);
}

// ---------------------------------------------------------------------------
// multi-tensor absmax: one dispatch for all 13 input tensors
// ---------------------------------------------------------------------------
struct AMDesc { const float* p; long n4; int slot; };
struct AMBatch { AMDesc d[13]; };
__global__ __launch_bounds__(256) void absmax_multi_kernel(AMBatch bt, float* ws) {
  AMDesc d = bt.d[blockIdx.y];
  float m = 0.f;
  long stride = (long)gridDim.x * 256;
  for (long i = (long)blockIdx.x * 256 + threadIdx.x; i < d.n4; i += stride) {
    float4 v = ((const float4*)d.p)[i];
    m = fmaxf(m, fmaxf(fmaxf(fabsf(v.x), fabsf(v.y)), fmaxf(fabsf(v.z), fabsf(v.w))));
  }
#pragma unroll
  for (int o = 32; o; o >>= 1) m = fmaxf(m, __shfl_down(m, o, 64));
  __shared__ float sm[4];
  if (!(threadIdx.x & 63)) sm[threadIdx.x >> 6] = m;
  __syncthreads();
  if (threadIdx.x == 0)
    atomicMaxF(ws + d.slot, fmaxf(fmaxf(sm[0], sm[1]), fmaxf(sm[2], sm[3])));
}

// multi-tensor fake-quant -> i8 codes (x + 6 weights)
struct QMDesc { const float* in; signed char* out; long n4; int slot; float qmin; };
struct QMBatch { QMDesc d[7]; };
__global__ __launch_bounds__(256) void quant8_multi_kernel(QMBatch bt, const float* ws) {
  QMDesc d = bt.d[blockIdx.y];
  float scale = fmaxf(ws[d.slot] / 127.f, 1e-8f);
  long stride = (long)gridDim.x * 256;
  for (long i = (long)blockIdx.x * 256 + threadIdx.x; i < d.n4; i += stride) {
    float4 v = ((const float4*)d.in)[i];
    char4 o;
    o.x = (signed char)(int)fminf(fmaxf(rintf(v.x / scale), d.qmin), 127.f);
    o.y = (signed char)(int)fminf(fmaxf(rintf(v.y / scale), d.qmin), 127.f);
    o.z = (signed char)(int)fminf(fmaxf(rintf(v.z / scale), d.qmin), 127.f);
    o.w = (signed char)(int)fminf(fmaxf(rintf(v.w / scale), d.qmin), 127.f);
    ((char4*)d.out)[i] = o;
  }
}

// multi-tensor bias fake-quant -> fp32
struct BDesc { const float* in; float* out; int n4; int slot; };
struct BBatch { BDesc d[6]; };
__global__ __launch_bounds__(256) void bias_quant_multi_kernel(BBatch bt, const float* ws) {
  BDesc d = bt.d[blockIdx.y];
  float scale = fmaxf(ws[d.slot] / 127.f, 1e-8f);
  int i = blockIdx.x * 256 + threadIdx.x;
  if (i < d.n4) {
    float4 v = ((const float4*)d.in)[i];
    float4 o;
    o.x = fminf(fmaxf(rintf(v.x / scale), -128.f), 127.f) * scale;
    o.y = fminf(fmaxf(rintf(v.y / scale), -128.f), 127.f) * scale;
    o.z = fminf(fmaxf(rintf(v.z / scale), -128.f), 127.f) * scale;
    o.w = fminf(fmaxf(rintf(v.w / scale), -128.f), 127.f) * scale;
    ((float4*)d.out)[i] = o;
  }
}

// generic fake-quant -> i8 (same layout)
__global__ __launch_bounds__(256) void quant8_kernel(const float* __restrict__ in,
                                                     signed char* __restrict__ out8, long n4,
                                                     const float* __restrict__ amax_p,
                                                     float pre, float qmin) {
  float scale = fmaxf(amax_p[0] * pre / 127.f, 1e-8f);
  long stride = (long)gridDim.x * 256;
  for (long i = (long)blockIdx.x * 256 + threadIdx.x; i < n4; i += stride) {
    float4 v = ((const float4*)in)[i];
    char4 o;
    o.x = (signed char)(int)fminf(fmaxf(rintf(v.x * pre / scale), qmin), 127.f);
    o.y = (signed char)(int)fminf(fmaxf(rintf(v.y * pre / scale), qmin), 127.f);
    o.z = (signed char)(int)fminf(fmaxf(rintf(v.z * pre / scale), qmin), 127.f);
    o.w = (signed char)(int)fminf(fmaxf(rintf(v.w * pre / scale), qmin), 127.f);
    ((char4*)out8)[i] = o;
  }
}

// relu + unsigned 8-bit quant -> codes stored as (c - 128) in signed i8
__global__ __launch_bounds__(256) void relu_quant8_kernel(const float* __restrict__ in,
                                                          signed char* __restrict__ out8, long n4,
                                                          const float* __restrict__ amax_p) {
  float scale = fmaxf(amax_p[0] / 255.f, 1e-8f);
  long stride = (long)gridDim.x * 256;
  for (long i = (long)blockIdx.x * 256 + threadIdx.x; i < n4; i += stride) {
    float4 v = ((const float4*)in)[i];
    char4 o;
    o.x = (signed char)((int)fminf(fmaxf(rintf(fmaxf(v.x, 0.f) / scale), 0.f), 255.f) - 128);
    o.y = (signed char)((int)fminf(fmaxf(rintf(fmaxf(v.y, 0.f) / scale), 0.f), 255.f) - 128);
    o.z = (signed char)((int)fminf(fmaxf(rintf(fmaxf(v.z, 0.f) / scale), 0.f), 255.f) - 128);
    o.w = (signed char)((int)fminf(fmaxf(rintf(fmaxf(v.w, 0.f) / scale), 0.f), 255.f) - 128);
    ((char4*)out8)[i] = o;
  }
}

// per-row sum of int8 codes (for unsigned-offset correction); one block per row
__global__ __launch_bounds__(256) void rowsum_i8_kernel(const signed char* __restrict__ w8,
                                                        int* __restrict__ out, int Kdim) {
  const int row = blockIdx.x, t = threadIdx.x;
  const signed char* p = w8 + (long)row * Kdim;
  int s = 0;
  for (int i = t * 16; i < Kdim; i += 4096) {
    int4v v = *(const int4v*)(p + i);
    const signed char* b = (const signed char*)&v;
#pragma unroll
    for (int j = 0; j < 16; j++) s += b[j];
  }
#pragma unroll
  for (int o = 32; o; o >>= 1) s += __shfl_down(s, o, 64);
  __shared__ int sm[4];
  if (!(t & 63)) sm[t >> 6] = s;
  __syncthreads();
  if (t == 0) out[row] = sm[0] + sm[1] + sm[2] + sm[3];
}

// ---------------------------------------------------------------------------
// int8 MFMA NT GEMM (exact): C[M,N] = (sum_k A8[m,k]*B8[n,k] + corr) * s_a*s_b + bias[n]
//
// R5-EXACT REVERT (best measured config: 48.7us/dispatch, FETCH 24.7MB,
// VGPR 36, zero bank conflicts, zero spill). R7/R8 falsified the smaller-tile
// family (64x64, 64x128): occupancy gains are outweighed by L2/L3 thrash
// (FETCH 24.7 -> 39-68MB). 128x128, 512 threads, 8 waves 4x2 spatial (32x64
// per wave, acc[2][4]=32 regs), BK=64, 2-buffer counted vmcnt(2).
// ---------------------------------------------------------------------------
__global__ __launch_bounds__(512, 2) void gemm_i8_kernel(
    const signed char* __restrict__ A, const signed char* __restrict__ Bw,
    const float* __restrict__ biasq,
    const float* __restrict__ amax_a, float div_a,
    const float* __restrict__ amax_b,
    const int* __restrict__ rowsum,           // nullable: adds 128*rowsum[n]
    float* __restrict__ C, int M, int N, int K,
    float* __restrict__ amax_out, int relu_amax, int mode) {
  __shared__ signed char Asm[2][8192];  // 128 rows x 64B, K-contiguous
  __shared__ signed char Bsm[2][8192];
  __shared__ float redm[8];
  const int t = threadIdx.x;
  // XCD-aware swizzle (gridDim.y % 8 == 0): xcd gets M-band [xcd*gy/8 .. )
  int bx, by;
  {
    int lin = blockIdx.y * gridDim.x + blockIdx.x;
    if ((gridDim.y & 7) == 0) {
      int xcd = lin & 7, j = lin >> 3;
      bx = j % gridDim.x;
      by = (gridDim.y >> 3) * xcd + j / gridDim.x;
    } else { bx = blockIdx.x; by = blockIdx.y; }
  }
  const int m0 = by * 128, n0 = bx * 128;
  const int w = t >> 6, lane = t & 63;
  const int fr = lane & 15, quad = lane >> 4;
  const int wm = w >> 1, wn = w & 1;    // 4x2 spatial: wave owns rows wm*32, cols wn*64
  const int r0 = t >> 2;                // staging row 0..127 (512 threads)
  // Swizzle: LDS(row r, slot s) holds global(row r, slot s ^ ((r>>1)&3)).
  const int csrc = (((t & 3) ^ ((t >> 3) & 3)) << 4);
  // Read side: LDS slot = quad ^ ((fr>>1)&3) (same involution).
  const int sx = ((quad ^ ((fr >> 1) & 3)) << 4);

  int4v acc[2][4];
#pragma unroll
  for (int r = 0; r < 2; r++)
#pragma unroll
    for (int c = 0; c < 4; c++) acc[r][c] = (int4v){0, 0, 0, 0};

  const long arow = (long)(m0 + r0) * K + csrc;
  const long brow = (long)(n0 + r0) * K + csrc;

  auto stage = [&](int buf, int kt) {
    const int kk = kt << 6;
    gl2lds16(A + arow + kk, Asm[buf] + t * 16);
    gl2lds16(Bw + brow + kk, Bsm[buf] + t * 16);
  };
  auto compute = [&](int buf) {
    int4v af[2], bf[4];
#pragma unroll
    for (int r = 0; r < 2; r++)
      af[r] = *(const int4v*)(Asm[buf] + (wm * 32 + r * 16 + fr) * 64 + sx);
#pragma unroll
    for (int c = 0; c < 4; c++)
      bf[c] = *(const int4v*)(Bsm[buf] + (wn * 64 + c * 16 + fr) * 64 + sx);
#pragma unroll
    for (int r = 0; r < 2; r++)
#pragma unroll
      for (int c = 0; c < 4; c++)
        acc[r][c] = __builtin_amdgcn_mfma_i32_16x16x64_i8(af[r], bf[c], acc[r][c], 0, 0, 0);
  };

  const int nt = K >> 6;  // 16 (K=1024) or 64 (K=4096)
  stage(0, 0);
  int buf = 0;
  for (int kt = 0; kt < nt; ++kt) {
    if (kt + 1 < nt) {
      stage(buf ^ 1, kt + 1);  // buf^1's previous readers all passed last barrier
      __asm__ volatile("s_waitcnt vmcnt(2)" ::: "memory");  // tile kt resident (this wave)
    } else {
      __asm__ volatile("s_waitcnt vmcnt(0)" ::: "memory");
    }
    RAW_BARRIER();             // -> tile kt resident for ALL waves
    compute(buf);
    RAW_BARRIER();             // all waves' ds_reads of buf done -> re-stageable
    buf ^= 1;
  }

  // --- epilogue ---
  const int seg = (mode == 1) ? (n0 >> 10) : 0;
  const float s_a = fmaxf(amax_a[0] / div_a, 1e-8f);
  const float s_b = fmaxf(amax_b[seg] / 127.f, 1e-8f);
  const float s = s_a * s_b;
  float lmax = 0.f;
#pragma unroll
  for (int r = 0; r < 2; r++) {
    int rbase = m0 + wm * 32 + r * 16 + quad * 4;
#pragma unroll
    for (int c = 0; c < 4; c++) {
      int col = n0 + wn * 64 + c * 16 + fr;
      int corr = rowsum ? (rowsum[col] << 7) : 0;
      float bi = biasq[col];
      if (mode == 1) {
        // segment-local fp32 [B,H,S,D] write
        int h = (col >> 6) & 15, dd = col & 63;
        float* cbase = C + (long)seg * ((long)TB_ROWS * TB_E);
#pragma unroll
        for (int g = 0; g < 4; g++) {
          int m = rbase + g;
          int b = m >> 10, sdx = m & 1023;
          float o = (float)acc[r][c][g] * s + bi;
          lmax = fmaxf(lmax, fabsf(o));
          cbase[((((long)b * TB_H + h) * TB_S) + sdx) * TB_D + dd] = o;
        }
      } else {
#pragma unroll
        for (int g = 0; g < 4; g++) {
          float o = (float)(acc[r][c][g] + corr) * s + bi;
          lmax = fmaxf(lmax, relu_amax ? fmaxf(o, 0.f) : fabsf(o));
          C[(long)(rbase + g) * N + col] = o;
        }
      }
    }
  }
#pragma unroll
  for (int o = 32; o; o >>= 1) lmax = fmaxf(lmax, __shfl_down(lmax, o, 64));
  if (!lane) redm[w] = lmax;
  __syncthreads();
  if (t == 0) {
    float m01 = fmaxf(fmaxf(redm[0], redm[1]), fmaxf(redm[2], redm[3]));
    float m23 = fmaxf(fmaxf(redm[4], redm[5]), fmaxf(redm[6], redm[7]));
    atomicMaxF(amax_out + seg, fmaxf(m01, m23));
  }
}

// ---------------------------------------------------------------------------
// v quant + transpose: fp32 [B,H,S,D] -> i8 blocked [BH][jb][D][64]
// ---------------------------------------------------------------------------
__global__ __launch_bounds__(256) void quant8_vb_kernel(const float* __restrict__ v,
                                                        const float* __restrict__ amax_p,
                                                        signed char* __restrict__ v8b) {
  __shared__ signed char tile[64][80];  // [d][s], stride 80
  const int bh = blockIdx.x;
  const int jb = blockIdx.y;
  const int s0 = jb * 64;
  const int t = threadIdx.x;
  const float scale = fmaxf(amax_p[0] / 127.f, 1e-8f);
#pragma unroll
  for (int it = 0; it < 4; it++) {
    int idx = t + it * 256;           // 0..1023 float4 slots
    int r = idx >> 4, c4 = (idx & 15) * 4;
    float4 vv = *(const float4*)(v + ((long)bh * TB_S + s0 + r) * TB_D + c4);
    tile[c4 + 0][r] = (signed char)(int)fminf(fmaxf(rintf(vv.x / scale), -128.f), 127.f);
    tile[c4 + 1][r] = (signed char)(int)fminf(fmaxf(rintf(vv.y / scale), -128.f), 127.f);
    tile[c4 + 2][r] = (signed char)(int)fminf(fmaxf(rintf(vv.z / scale), -128.f), 127.f);
    tile[c4 + 3][r] = (signed char)(int)fminf(fmaxf(rintf(vv.w / scale), -128.f), 127.f);
  }
  __syncthreads();
  int d = t >> 2, sb = (t & 3) * 16;
  int4v o = *(const int4v*)&tile[d][sb];
  *(int4v*)(v8b + (((long)bh * 16 + jb) * 64 + d) * 64 + sb) = o;
}

// ---------------------------------------------------------------------------
// Attention pass A: per-row signed int max of scores -> irowmax; global int
// absmax -> imax_out. q8/k8 in [B,H,S,D].
// R8 post-mortem: the j+=16 loop exposed one full L2 load latency per tile
// (load -> MFMA -> reduce serial chain x64 iters). Batch x4: issue 4
// independent kf loads, then 4 MFMAs, then reduce -> latency amortized 4x.
// ---------------------------------------------------------------------------
__global__ __launch_bounds__(256) void attn_rowmax_kernel(const signed char* __restrict__ q8,
                                                          const signed char* __restrict__ k8,
                                                          int* __restrict__ irowmax,
                                                          int* __restrict__ imax_out) {
  const int bh = blockIdx.x;
  const int t = threadIdx.x, w = t >> 6, lane = t & 63;
  const int fr = lane & 15, quad = lane >> 4;
  const int i0 = blockIdx.y * 64 + w * 16;
  const long base = (long)bh * TB_S;
  int4v qf = *(const int4v*)(q8 + (base + i0 + fr) * 64 + quad * 16);
  int mx = -2147483647, mn = 2147483647;
  for (int j0 = 0; j0 < TB_S; j0 += 64) {
    int4v kf[4], sc[4];
#pragma unroll
    for (int tt = 0; tt < 4; tt++)
      kf[tt] = *(const int4v*)(k8 + (base + j0 + tt * 16 + fr) * 64 + quad * 16);
#pragma unroll
    for (int tt = 0; tt < 4; tt++)
      sc[tt] = __builtin_amdgcn_mfma_i32_16x16x64_i8(kf[tt], qf, (int4v){0, 0, 0, 0}, 0, 0, 0);
#pragma unroll
    for (int tt = 0; tt < 4; tt++) {
      mx = max(mx, max(max(sc[tt][0], sc[tt][1]), max(sc[tt][2], sc[tt][3])));
      mn = min(mn, min(min(sc[tt][0], sc[tt][1]), min(sc[tt][2], sc[tt][3])));
    }
  }
  mx = max(mx, __shfl_xor(mx, 16, 64));
  mx = max(mx, __shfl_xor(mx, 32, 64));
  mn = min(mn, __shfl_xor(mn, 16, 64));
  mn = min(mn, __shfl_xor(mn, 32, 64));
  if (quad == 0) irowmax[(long)bh * TB_S + i0 + fr] = mx;
  int gm = max(mx, -mn);
#pragma unroll
  for (int o = 32; o; o >>= 1) gm = max(gm, __shfl_down(gm, o, 64));
  __shared__ int sm[4];
  if (!lane) sm[w] = gm;
  __syncthreads();
  if (t == 0) atomicMax(imax_out, max(max(sm[0], sm[1]), max(sm[2], sm[3])));
}

// ---------------------------------------------------------------------------
// Attention pass B: l = sum exp2((qv - qmax)*aa) per row. rowl <- l;
// amax_attn <- max(1/l). Batched x4 like pass A (load-latency amortization).
// NOTE: the qv clamps to [-128,127] are mathematically dead (|sc| <= imax ->
// |sc*c1| <= 127); pass C's clamped form computes identical values.
// ---------------------------------------------------------------------------
__global__ __launch_bounds__(256) void attn_rowsum_kernel(
    const signed char* __restrict__ q8, const signed char* __restrict__ k8,
    const int* __restrict__ irowmax, const int* __restrict__ imax_p,
    const float* __restrict__ amax_q, const float* __restrict__ amax_k,
    float* __restrict__ rowl, float* __restrict__ amax_attn) {
  const int bh = blockIdx.x;
  const int t = threadIdx.x, w = t >> 6, lane = t & 63;
  const int fr = lane & 15, quad = lane >> 4;
  const int i0 = blockIdx.y * 64 + w * 16;
  const float s_q = fmaxf(amax_q[0] * 0.125f / 127.f, 1e-8f);
  const float s_k = fmaxf(amax_k[0] / 127.f, 1e-8f);
  const float sqk = s_q * s_k;
  const float s_sc = fmaxf((float)imax_p[0] * sqk / 127.f, 1e-8f);
  const float c1 = sqk / s_sc;
  const float aa = s_sc * 1.44269504088896340736f;
  const long base = (long)bh * TB_S;
  int4v qf = *(const int4v*)(q8 + (base + i0 + fr) * 64 + quad * 16);
  const int imr = irowmax[base + i0 + fr];
  const float qmax = fminf(fmaxf(rintf((float)imr * c1), -128.f), 127.f);
  const float qa = qmax * aa;
  float l = 0.f;
  for (int j0 = 0; j0 < TB_S; j0 += 64) {
    int4v kf[4], sc[4];
#pragma unroll
    for (int tt = 0; tt < 4; tt++)
      kf[tt] = *(const int4v*)(k8 + (base + j0 + tt * 16 + fr) * 64 + quad * 16);
#pragma unroll
    for (int tt = 0; tt < 4; tt++)
      sc[tt] = __builtin_amdgcn_mfma_i32_16x16x64_i8(kf[tt], qf, (int4v){0, 0, 0, 0}, 0, 0, 0);
#pragma unroll
    for (int tt = 0; tt < 4; tt++) {
#pragma unroll
      for (int g = 0; g < 4; g++) {
        float qv = rintf((float)sc[tt][g] * c1);   // clamps dead: |sc*c1| <= 127
        l += fast_exp2(fmaf(qv, aa, -qa));
      }
    }
  }
  l += __shfl_xor(l, 16, 64);
  l += __shfl_xor(l, 32, 64);
  if (quad == 0) rowl[base + i0 + fr] = l;
  float inv = 1.f / l;                        // row max of softmax = 1/l
#pragma unroll
  for (int o = 32; o; o >>= 1) inv = fmaxf(inv, __shfl_down(inv, o, 64));
  __shared__ float smf[4];
  if (!lane) smf[w] = inv;
  __syncthreads();
  if (t == 0) atomicMaxF(amax_attn, fmaxf(fmaxf(smf[0], smf[1]), fmaxf(smf[2], smf[3])));
}

// ---------------------------------------------------------------------------
// Attention pass C: recompute scores (identical expr -> identical codes),
// attn code = rint(exp2(qv*aa - bexp) * invls); per-wave LDS transpose (no
// block barriers); PV MFMA on blocked v8b. ctx fp32 [B,S,H,D] + fused absmax.
// (R5-exact, the measured-best 46.1us form.)
// ---------------------------------------------------------------------------
__global__ __launch_bounds__(256) void attn_pv_kernel(
    const signed char* __restrict__ q8, const signed char* __restrict__ k8,
    const signed char* __restrict__ v8b,
    const int* __restrict__ irowmax, const int* __restrict__ imax_p,
    const float* __restrict__ amax_q, const float* __restrict__ amax_k,
    const float* __restrict__ amax_v, const float* __restrict__ amax_attn,
    const float* __restrict__ rowl,
    float* __restrict__ ctx, float* __restrict__ amax_ctx) {
  __shared__ signed char latt[4][16][80];  // [wave][i-rel][j-byte], stride 80
  const int bh = blockIdx.x, b = bh >> 4, h = bh & 15;
  const int t = threadIdx.x, w = t >> 6, lane = t & 63;
  const int fr = lane & 15, quad = lane >> 4;
  const int i0 = blockIdx.y * 64 + w * 16;
  const float s_q = fmaxf(amax_q[0] * 0.125f / 127.f, 1e-8f);
  const float s_k = fmaxf(amax_k[0] / 127.f, 1e-8f);
  const float sqk = s_q * s_k;
  const float s_sc = fmaxf((float)imax_p[0] * sqk / 127.f, 1e-8f);
  const float c1 = sqk / s_sc;
  const float aa = s_sc * 1.44269504088896340736f;
  const float s_v = fmaxf(amax_v[0] / 127.f, 1e-8f);
  const float s_at = fmaxf(amax_attn[0] / 127.f, 1e-8f);
  const long base = (long)bh * TB_S;
  int4v qf = *(const int4v*)(q8 + (base + i0 + fr) * 64 + quad * 16);
  const int imr = irowmax[base + i0 + fr];
  const float qmax = fminf(fmaxf(rintf((float)imr * c1), -128.f), 127.f);
  const float bexp = qmax * aa;
  const float li = rowl[base + i0 + fr];
  const float invls = 1.f / (li * s_at);             // one exact div per row
  int4v accv[4];
#pragma unroll
  for (int dtile = 0; dtile < 4; dtile++) accv[dtile] = (int4v){0, 0, 0, 0};

  for (int j0 = 0; j0 < TB_S; j0 += 64) {
#pragma unroll
    for (int tt = 0; tt < 4; tt++) {
      int4v kf = *(const int4v*)(k8 + (base + j0 + tt * 16 + fr) * 64 + quad * 16);
      int4v sc = __builtin_amdgcn_mfma_i32_16x16x64_i8(kf, qf, (int4v){0, 0, 0, 0}, 0, 0, 0);
      int packed = 0;
#pragma unroll
      for (int g = 0; g < 4; g++) {
        float qv = fminf(fmaxf(rintf((float)sc[g] * c1), -128.f), 127.f);
        float e = fast_exp2(fmaf(qv, aa, -bexp));
        int code = (int)fminf(fmaxf(rintf(e * invls), -128.f), 127.f);
        packed |= (code & 255) << (g * 8);
      }
      *(int*)&latt[w][fr][tt * 16 + quad * 4] = packed;
    }
    LGKM0();   // wave-private LDS: ds in-order per wave, no block barrier needed
    int4v af = *(const int4v*)&latt[w][fr][quad * 16];
    const signed char* vbase = v8b + (((long)bh * 16 + (j0 >> 6)) * 64) * 64;
#pragma unroll
    for (int dtile = 0; dtile < 4; dtile++) {
      int4v vf = *(const int4v*)(vbase + (dtile * 16 + fr) * 64 + quad * 16);
      accv[dtile] = __builtin_amdgcn_mfma_i32_16x16x64_i8(af, vf, accv[dtile], 0, 0, 0);
    }
    CMEMBAR(); // keep next iteration's ds_writes after this read (in-order DS)
  }
  const float sav = s_at * s_v;
  float cmax = 0.f;
#pragma unroll
  for (int dtile = 0; dtile < 4; dtile++) {
#pragma unroll
    for (int g = 0; g < 4; g++) {
      float val = (float)accv[dtile][g] * sav;
      cmax = fmaxf(cmax, fabsf(val));
      int irow = i0 + quad * 4 + g;
      ctx[(((long)(b * TB_S + irow)) * TB_H + h) * TB_D + dtile * 16 + fr] = val;
    }
  }
#pragma unroll
  for (int o = 32; o; o >>= 1) cmax = fmaxf(cmax, __shfl_down(cmax, o, 64));
  __shared__ float smf[4];
  if (!lane) smf[w] = cmax;
  __syncthreads();
  if (t == 0) atomicMaxF(amax_ctx, fmaxf(fmaxf(smf[0], smf[1]), fmaxf(smf[2], smf[3])));
}

// ---------------------------------------------------------------------------
// h = LayerNorm(dequant(a8) + fakequant(braw)); fused output absmax.
// Wave-per-row (4 rows/block), single-pass sum+sumsq (var = E[x^2]-mu^2),
// no block barriers in the main path.
// ---------------------------------------------------------------------------
__global__ __launch_bounds__(256) void resid_ln_kernel(const signed char* __restrict__ a8,
                                                       const float* __restrict__ amax_a,
                                                       const float* __restrict__ braw,
                                                       const float* __restrict__ amax_b,
                                                       float* __restrict__ outp,
                                                       float* __restrict__ amax_out) {
  const int t = threadIdx.x, w = t >> 6, lane = t & 63;
  const int row = blockIdx.x * 4 + w;
  const float sa = fmaxf(amax_a[0] / 127.f, 1e-8f);
  const float sb = fmaxf(amax_b[0] / 127.f, 1e-8f);
  const long base = (long)row * TB_E;
  float v[16];
  float s = 0.f, q = 0.f;
#pragma unroll
  for (int j = 0; j < 4; j++) {
    char4 a = ((const char4*)(a8 + base))[j * 64 + lane];
    float4 bv = *(const float4*)(braw + base + j * 256 + lane * 4);
    float x0 = (float)a.x * sa + fminf(fmaxf(rintf(bv.x / sb), -128.f), 127.f) * sb;
    float x1 = (float)a.y * sa + fminf(fmaxf(rintf(bv.y / sb), -128.f), 127.f) * sb;
    float x2 = (float)a.z * sa + fminf(fmaxf(rintf(bv.z / sb), -128.f), 127.f) * sb;
    float x3 = (float)a.w * sa + fminf(fmaxf(rintf(bv.w / sb), -128.f), 127.f) * sb;
    v[j * 4 + 0] = x0; v[j * 4 + 1] = x1; v[j * 4 + 2] = x2; v[j * 4 + 3] = x3;
    s += (x0 + x1) + (x2 + x3);
    q += (x0 * x0 + x1 * x1) + (x2 * x2 + x3 * x3);
  }
  // dual wave-allreduce (independent chains -> ILP overlap)
#pragma unroll
  for (int o = 32; o; o >>= 1) {
    s += __shfl_xor(s, o, 64);
    q += __shfl_xor(q, o, 64);
  }
  const float mu = s * (1.f / TB_E);
  const float var = fmaxf(q * (1.f / TB_E) - mu * mu, 0.f);
  const float rs = 1.f / sqrtf(var + 1e-5f);
  float lm = 0.f;
#pragma unroll
  for (int j = 0; j < 4; j++) {
    float4 o4;
    o4.x = (v[j * 4 + 0] - mu) * rs;
    o4.y = (v[j * 4 + 1] - mu) * rs;
    o4.z = (v[j * 4 + 2] - mu) * rs;
    o4.w = (v[j * 4 + 3] - mu) * rs;
    *(float4*)(outp + base + j * 256 + lane * 4) = o4;
    lm = fmaxf(lm, fmaxf(fmaxf(fabsf(o4.x), fabsf(o4.y)), fmaxf(fabsf(o4.z), fabsf(o4.w))));
  }
#pragma unroll
  for (int o = 32; o; o >>= 1) lm = fmaxf(lm, __shfl_down(lm, o, 64));
  __shared__ float redm[4];
  if (!lane) redm[w] = lm;
  __syncthreads();
  if (t == 0) atomicMaxF(amax_out, fmaxf(fmaxf(redm[0], redm[1]), fmaxf(redm[2], redm[3])));
}

// ---------------------------------------------------------------------------
// Host side
// ---------------------------------------------------------------------------
#define SL_X 0
#define SL_WQ 1
#define SL_WK 2
#define SL_WV 3
#define SL_WO 4
#define SL_W1 5
#define SL_W2 6
#define SL_BQ 7
#define SL_BK 8
#define SL_BV 9
#define SL_BO 10
#define SL_B1 11
#define SL_B2 12
#define SL_Q 13   // SL_K = 14, SL_V = 15 must stay consecutive (QKV epilogue)
#define SL_K 14
#define SL_V 15
#define SL_SCI 16     // int imax of scores
#define SL_ATTN 17
#define SL_CTX 18
#define SL_AO 19
#define SL_H 20
#define SL_RELU 21
#define SL_M2 22
#define SL_DUMMY 23

static inline int nblocks(long n) {
  long b = (n + 255) / 256;
  return (int)(b > 2048 ? 2048 : b);
}

extern "C" void kernel_launch(void* const* d_in, const int* in_sizes, int n_in,
                              void* d_out, int out_size, void* d_ws, size_t ws_size,
                              hipStream_t stream) {
  const float* x  = (const float*)d_in[0];
  const float* Wq = (const float*)d_in[1];
  const float* bq = (const float*)d_in[2];
  const float* Wk = (const float*)d_in[3];
  const float* bk = (const float*)d_in[4];
  const float* Wv = (const float*)d_in[5];
  const float* bv = (const float*)d_in[6];
  const float* Wo = (const float*)d_in[7];
  const float* bo = (const float*)d_in[8];
  const float* W1 = (const float*)d_in[9];
  const float* b1 = (const float*)d_in[10];
  const float* W2 = (const float*)d_in[11];
  const float* b2 = (const float*)d_in[12];
  float* ws = (float*)d_ws;
  float* out = (float*)d_out;

  const long SZ_XE = (long)TB_ROWS * TB_E;      // 4,194,304
  const long SZ_W  = (long)TB_E * TB_E;         // 1,048,576
  const long SZ_M1 = (long)TB_ROWS * TB_MLP;    // 16,777,216

  // float-offset layout
  const long OFF_QBQ = 1024, OFF_QBK = 2048, OFF_QBV = 3072, OFF_QBO = 4096;
  const long OFF_QB1 = 5120, OFF_QB2 = 9216;
  const long OFF_RSUM = 10240;                  // int32[1024]
  const long OFF_Q  = 65536;                    // fp32 q [B,H,S,D], later ctx
  const long OFF_K  = OFF_Q + SZ_XE;            // fp32 k [B,H,S,D], later attn_out
  const long OFF_V  = OFF_K + SZ_XE;            // fp32 v [B,H,S,D], later h
  const long OFF_M2 = OFF_V + SZ_XE;            // fp32 m2
  const long OFF_IRM = OFF_M2 + SZ_XE;          // int irowmax [65536]
  const long OFF_ROWL = OFF_IRM + 65536;
  const long OFF_M1 = OFF_ROWL + 65536;         // fp32 m1 (64MB)
  const long OFF_I8 = OFF_M1 + SZ_M1;           // i8 region start (float offset)

  float* qbuf = ws + OFF_Q;  float* kbuf = ws + OFF_K;  float* vbuf = ws + OFF_V;
  float* m2   = ws + OFF_M2;
  int*   irowmax = (int*)(ws + OFF_IRM);
  float* rowl = ws + OFF_ROWL;
  float* m1 = ws + OFF_M1;
  float* ctx = qbuf;        // reuse q (q8 codes already extracted)
  float* attn_out = kbuf;   // reuse k
  float* hbuf = vbuf;       // reuse v
  float* qbq_ = ws + OFF_QBQ; float* qbk_ = ws + OFF_QBK;
  float* qbv_ = ws + OFF_QBV; float* qbo_ = ws + OFF_QBO;
  float* qb1_ = ws + OFF_QB1; float* qb2_ = ws + OFF_QB2;
  int* rsum = (int*)(ws + OFF_RSUM);
  int* imax = (int*)(ws + SL_SCI);

  // i8 code buffers (byte pointers)
  signed char* i8base = (signed char*)(ws + OFF_I8);
  signed char* qx8  = i8base;                   // 4096x1024 [rows,E]
  signed char* wq8  = qx8 + SZ_XE;              // 1024x1024  (wq8,wk8,wv8 contiguous for QKV fusion)
  signed char* wk8  = wq8 + SZ_W;
  signed char* wv8  = wk8 + SZ_W;
  signed char* wo8  = wv8 + SZ_W;
  signed char* w18  = wo8 + SZ_W;               // 4096x1024
  signed char* w28  = w18 + SZ_XE;              // 1024x4096
  signed char* ctx8 = w28 + SZ_XE;              // 4096x1024
  signed char* m08  = ctx8 + SZ_XE;             // 4096x1024
  signed char* m18  = m08 + SZ_XE;              // 4096x4096 (relu codes - 128)
  signed char* q8   = m18 + SZ_M1;              // [B,H,S,D]
  signed char* k8   = q8 + SZ_XE;               // [B,H,S,D]
  signed char* v8b  = k8 + SZ_XE;               // [BH][16][64][64]

  hipMemsetAsync(ws, 0, 4096, stream);  // zero scalar slots

  // --- absmax of all 13 inputs (1 dispatch) ---
  AMBatch am;
  am.d[0]  = {x,  SZ_XE/4, SL_X};
  am.d[1]  = {Wq, SZ_W/4,  SL_WQ};
  am.d[2]  = {Wk, SZ_W/4,  SL_WK};
  am.d[3]  = {Wv, SZ_W/4,  SL_WV};
  am.d[4]  = {Wo, SZ_W/4,  SL_WO};
  am.d[5]  = {W1, SZ_XE/4, SL_W1};
  am.d[6]  = {W2, SZ_XE/4, SL_W2};
  am.d[7]  = {bq, 256,     SL_BQ};
  am.d[8]  = {bk, 256,     SL_BK};
  am.d[9]  = {bv, 256,     SL_BV};
  am.d[10] = {bo, 256,     SL_BO};
  am.d[11] = {b1, 1024,    SL_B1};
  am.d[12] = {b2, 256,     SL_B2};
  absmax_multi_kernel<<<dim3(64, 13), 256, 0, stream>>>(am, ws);

  // --- quantize x + 6 weights to i8 codes (1 dispatch); biases (1 dispatch) ---
  QMBatch qm;
  qm.d[0] = {x,  qx8, SZ_XE/4, SL_X,  -128.f};
  qm.d[1] = {Wq, wq8, SZ_W/4,  SL_WQ, -127.f};
  qm.d[2] = {Wk, wk8, SZ_W/4,  SL_WK, -127.f};
  qm.d[3] = {Wv, wv8, SZ_W/4,  SL_WV, -127.f};
  qm.d[4] = {W1, w18, SZ_XE/4, SL_W1, -127.f};
  qm.d[5] = {W2, w28, SZ_XE/4, SL_W2, -127.f};
  qm.d[6] = {Wo, wo8, SZ_W/4,  SL_WO, -127.f};
  quant8_multi_kernel<<<dim3(64, 7), 256, 0, stream>>>(qm, ws);
  rowsum_i8_kernel<<<TB_E, 256, 0, stream>>>(w28, rsum, TB_MLP);
  BBatch bb;
  bb.d[0] = {bq, qbq_, 256,  SL_BQ};
  bb.d[1] = {bk, qbk_, 256,  SL_BK};
  bb.d[2] = {bv, qbv_, 256,  SL_BV};
  bb.d[3] = {bo, qbo_, 256,  SL_BO};
  bb.d[4] = {b1, qb1_, 1024, SL_B1};
  bb.d[5] = {b2, qb2_, 256,  SL_B2};
  bias_quant_multi_kernel<<<dim3(4, 6), 256, 0, stream>>>(bb, ws);

  // --- fused QKV in-projection (int8 MFMA, exact): N=3072, writes [B,H,S,D] fp32 ---
  gemm_i8_kernel<<<dim3(3*TB_E/128, TB_ROWS/128), 512, 0, stream>>>(
      qx8, wq8, qbq_, ws + SL_X, 127.f, ws + SL_WQ, nullptr, qbuf,
      TB_ROWS, 3*TB_E, TB_E, ws + SL_Q, 0, 1);

  // --- quantize q (pre=1/8), k (linear, layouts already [B,H,S,D]); v blocked ---
  quant8_kernel<<<2048, 256, 0, stream>>>(qbuf, q8, SZ_XE/4, ws + SL_Q, 0.125f, -128.f);
  quant8_kernel<<<2048, 256, 0, stream>>>(kbuf, k8, SZ_XE/4, ws + SL_K, 1.f, -128.f);
  quant8_vb_kernel<<<dim3(TB_B*TB_H, TB_S/64), 256, 0, stream>>>(vbuf, ws + SL_V, v8b);

  // --- attention (i8 MFMA, 3 passes) ---
  attn_rowmax_kernel<<<dim3(TB_B*TB_H, TB_S/64), 256, 0, stream>>>(q8, k8, irowmax, imax);
  attn_rowsum_kernel<<<dim3(TB_B*TB_H, TB_S/64), 256, 0, stream>>>(
      q8, k8, irowmax, imax, ws + SL_Q, ws + SL_K, rowl, ws + SL_ATTN);
  attn_pv_kernel<<<dim3(TB_B*TB_H, TB_S/64), 256, 0, stream>>>(
      q8, k8, v8b, irowmax, imax, ws + SL_Q, ws + SL_K, ws + SL_V, ws + SL_ATTN,
      rowl, ctx, ws + SL_CTX);

  // --- out projection ---
  quant8_kernel<<<2048, 256, 0, stream>>>(ctx, ctx8, SZ_XE/4, ws + SL_CTX, 1.f, -128.f);
  gemm_i8_kernel<<<dim3(TB_E/128, TB_ROWS/128), 512, 0, stream>>>(
      ctx8, wo8, qbo_, ws + SL_CTX, 127.f, ws + SL_WO, nullptr, attn_out,
      TB_ROWS, TB_E, TB_E, ws + SL_AO, 0, 0);

  // --- residual + LN (fused h absmax) ---
  resid_ln_kernel<<<TB_ROWS/4, 256, 0, stream>>>(qx8, ws + SL_X, attn_out, ws + SL_AO, hbuf, ws + SL_H);

  // --- MLP ---
  quant8_kernel<<<2048, 256, 0, stream>>>(hbuf, m08, SZ_XE/4, ws + SL_H, 1.f, -128.f);
  gemm_i8_kernel<<<dim3(TB_MLP/128, TB_ROWS/128), 512, 0, stream>>>(
      m08, w18, qb1_, ws + SL_H, 127.f, ws + SL_W1, nullptr, m1,
      TB_ROWS, TB_MLP, TB_E, ws + SL_RELU, 1, 0);
  relu_quant8_kernel<<<nblocks(SZ_M1/4), 256, 0, stream>>>(m1, m18, SZ_M1/4, ws + SL_RELU);
  gemm_i8_kernel<<<dim3(TB_E/128, TB_ROWS/128), 512, 0, stream>>>(
      m18, w28, qb2_, ws + SL_RELU, 255.f, ws + SL_W2, rsum, m2,
      TB_ROWS, TB_E, TB_MLP, ws + SL_M2, 0, 0);

  // --- final residual + LN ---
  resid_ln_kernel<<<TB_ROWS/4, 256, 0, stream>>>(m08, ws + SL_H, m2, ws + SL_M2, out, ws + SL_DUMMY);
}